// Round 4
// baseline (373.962 us; speedup 1.0000x reference)
//
#include <hip/hip_runtime.h>
#include <hip/hip_bf16.h>
#include <stdint.h>

// fp32 I/O. Conv3x3, 1x1 projections, and attention run as bf16 MFMA.
// Softmax stats (m,l) and P come from the SAME bf16 MFMA S path (unscaled
// attention -> near-argmax softmax; any S mismatch scales o by exp(dS)).
// Round 10: conv halo restructure (staged traffic 885->245MB).
// Round 11 (this): attn_pv v3 — L3-traffic + conflict fix.
//   Evidence: pv 72us staging 512MB V at ~8-10TB/s = L3-BW-bound (L2 4MB/XCD
//   can't hold the 8MB V set; FETCH only 37MB -> L3-served). Conflicts 5.25M
//   from 64B-row Vs/Ks reads (8 consecutive lanes alias one 16B slot mod 128).
//   - i-tile 128 (acc 4x8), grid 256 = 1 block/CU, 148KB LDS, 3-buffer
//     counted-vmcnt pipeline (conv-v3 pattern).
//   - XCD-group swizzle: bx&7 = (mb<<1)|seg -> the 32 i-blocks sharing one
//     1MB V-slice land on ONE XCD -> V/K L2-resident, L3 sees 8MB once.
//   - slot swizzles: V/K/Q ^((row>>1)&3), P XOR (il&7)<<4 -> 8 consecutive
//     lanes hit 8 distinct 16B slots (the conv-A pattern that measures 0).
//     Same read-swizzle fix applied to attn_stats.

constexpr int CINCH = 512;
constexpr int NPIX  = 4096;   // 64*64

typedef __bf16 bf16x8 __attribute__((ext_vector_type(8)));
typedef __bf16 bf16x4 __attribute__((ext_vector_type(4)));
typedef float  f32x4  __attribute__((ext_vector_type(4)));

__device__ __forceinline__ __bf16 f2b(float f) {
    __hip_bfloat16 h = __float2bfloat16(f);
    return *reinterpret_cast<__bf16*>(&h);
}

__device__ __forceinline__ void load_lds16(const void* g, void* l) {
    __builtin_amdgcn_global_load_lds(
        (const __attribute__((address_space(1))) unsigned int*)(uintptr_t)g,
        (__attribute__((address_space(3))) unsigned int*)(uintptr_t)l,
        16, 0, 0);
}

// ---------------------------------------------------------------------------
// Prep A: conv weights fp32 [oc][ic][9] -> Wt bf16 [mod][tap][oc][ic];
// BN scale/shift tables; zero row. grid 2307 x 256.
// ---------------------------------------------------------------------------
__global__ __launch_bounds__(256)
void prep_w(const float* __restrict__ w_r, const float* __restrict__ w_d,
            const float* __restrict__ cb_r, const float* __restrict__ bg_r,
            const float* __restrict__ bb_r, const float* __restrict__ bm_r,
            const float* __restrict__ bv_r,
            const float* __restrict__ cb_d, const float* __restrict__ bg_d,
            const float* __restrict__ bb_d, const float* __restrict__ bm_d,
            const float* __restrict__ bv_d,
            __bf16* __restrict__ Wt, float* __restrict__ scA,
            float* __restrict__ shB, __bf16* __restrict__ zrow)
{
    const int t = threadIdx.x;
    const int blk = blockIdx.x;
    if (blk < 2304) {
        int gid = blk * 1024 + t * 4;
        int mod = gid >= 1179648;
        int o2  = gid - mod * 1179648;
        int tap = o2 >> 17;
        int r   = o2 & 131071;
        int oc  = r >> 9;
        int ic  = r & 511;
        const float* wsrc = mod ? w_d : w_r;
        long base = ((long)(oc * 512 + ic)) * 9 + tap;
        bf16x4 v;
        v.x = f2b(wsrc[base]);
        v.y = f2b(wsrc[base + 9]);
        v.z = f2b(wsrc[base + 18]);
        v.w = f2b(wsrc[base + 27]);
        *(bf16x4*)&Wt[gid] = v;
    } else if (blk == 2304) {
        unsigned short* z = (unsigned short*)zrow;
        z[t] = 0; z[t + 256] = 0;
    } else {
        int mod = blk - 2305;
        const float* cb = mod ? cb_d : cb_r;
        const float* bg = mod ? bg_d : bg_r;
        const float* bb = mod ? bb_d : bb_r;
        const float* bm = mod ? bm_d : bm_r;
        const float* bv = mod ? bv_d : bv_r;
        int oc = t;
        float sc = bg[oc] * rsqrtf(bv[oc] + 1e-5f);
        scA[mod * 256 + oc] = sc;
        shB[mod * 256 + oc] = (cb[oc] - bm[oc]) * sc + bb[oc];
    }
}

// ---------------------------------------------------------------------------
// Prep B: projection weights fp32 -> bf16. Wq/Wk padded to 128 rows (zeros).
// ---------------------------------------------------------------------------
__global__ __launch_bounds__(256)
void prep_gw(const float* __restrict__ qw_r, const float* __restrict__ qw_d,
             const float* __restrict__ kw_r, const float* __restrict__ kw_d,
             const float* __restrict__ vw_r, const float* __restrict__ vw_d,
             const float* __restrict__ uw_r, const float* __restrict__ uw_d,
             __bf16* __restrict__ Wq, __bf16* __restrict__ Wk,
             __bf16* __restrict__ Wv, __bf16* __restrict__ Wu)
{
    int gid = blockIdx.x * 1024 + threadIdx.x * 4;
    __bf16* dst;
    float4 f = make_float4(0.f, 0.f, 0.f, 0.f);
    if (gid < 65536) {
        int mod = gid >> 15, e = gid & 32767;
        dst = Wq + gid;
        if (e < 8192) f = *(const float4*)((mod ? qw_d : qw_r) + e);
    } else if (gid < 131072) {
        int g = gid - 65536;
        int mod = g >> 15, e = g & 32767;
        dst = Wk + g;
        if (e < 8192) f = *(const float4*)((mod ? kw_d : kw_r) + e);
    } else if (gid < 262144) {
        int g = gid - 131072;
        int mod = g >> 16, e = g & 65535;
        dst = Wv + g;
        f = *(const float4*)((mod ? vw_d : vw_r) + e);
    } else {
        int g = gid - 262144;
        int mod = g >> 17, e = g & 131071;
        dst = Wu + g;
        f = *(const float4*)((mod ? uw_d : uw_r) + e);
    }
    bf16x4 o; o.x = f2b(f.x); o.y = f2b(f.y); o.z = f2b(f.z); o.w = f2b(f.w);
    *(bf16x4*)dst = o;
}

// ---------------------------------------------------------------------------
// Prep C: X fp32 [mod][b][512][4096] -> Xp bf16 [modb][4096pix][512ic]
// ---------------------------------------------------------------------------
__global__ __launch_bounds__(256)
void xpose(const float* __restrict__ inr, const float* __restrict__ ind,
           __bf16* __restrict__ Xp)
{
    __shared__ float tile[32][33];
    const int t = threadIdx.x;
    const int p0 = blockIdx.x * 32;
    const int ic0 = blockIdx.y * 32;
    const int mb = blockIdx.z;
    const int mod = mb >> 1, b = mb & 1;
    const float* src = (mod ? ind : inr) + (long)b * CINCH * NPIX;

    int i = t >> 3, j4 = (t & 7) * 4;
    float4 v = *(const float4*)&src[(long)(ic0 + i) * NPIX + p0 + j4];
    tile[i][j4 + 0] = v.x; tile[i][j4 + 1] = v.y;
    tile[i][j4 + 2] = v.z; tile[i][j4 + 3] = v.w;
    __syncthreads();
    int j = t >> 3, i4 = (t & 7) * 4;
    bf16x4 o;
    o.x = f2b(tile[i4 + 0][j]);
    o.y = f2b(tile[i4 + 1][j]);
    o.z = f2b(tile[i4 + 2][j]);
    o.w = f2b(tile[i4 + 3][j]);
    *(bf16x4*)&Xp[((long)mb * NPIX + p0 + j) * 512 + ic0 + i4] = o;
}

// ---------------------------------------------------------------------------
// fp32 [mb][256][4096] -> bf16 transposed [mb][4096][256]. grid (128, 8, 4).
// ---------------------------------------------------------------------------
__global__ __launch_bounds__(256)
void t256(const float* __restrict__ src, __bf16* __restrict__ dst)
{
    __shared__ float tile[32][33];
    const int t = threadIdx.x;
    const int p0 = blockIdx.x * 32;
    const int c0 = blockIdx.y * 32;
    const int mb = blockIdx.z;
    const float* s = src + (long)mb * 256 * NPIX;
    __bf16* d = dst + (long)mb * NPIX * 256;

    int i = t >> 3, j4 = (t & 7) * 4;
    float4 v = *(const float4*)&s[(long)(c0 + i) * NPIX + p0 + j4];
    tile[i][j4 + 0] = v.x; tile[i][j4 + 1] = v.y;
    tile[i][j4 + 2] = v.z; tile[i][j4 + 3] = v.w;
    __syncthreads();
    int j = t >> 3, i4 = (t & 7) * 4;
    bf16x4 o;
    o.x = f2b(tile[i4 + 0][j]); o.y = f2b(tile[i4 + 1][j]);
    o.z = f2b(tile[i4 + 2][j]); o.w = f2b(tile[i4 + 3][j]);
    *(bf16x4*)&d[((long)(p0 + j)) * 256 + c0 + i4] = o;
}

// ---------------------------------------------------------------------------
// Conv3x3 implicit-GEMM MFMA v3 (halo). Unchanged from round 10.
// ---------------------------------------------------------------------------
__global__ __launch_bounds__(256)
void conv_mfma(const __bf16* __restrict__ Wt, const __bf16* __restrict__ Xp,
               const __bf16* __restrict__ zrow, const float* __restrict__ scA,
               const float* __restrict__ shB, const float* __restrict__ prr,
               const float* __restrict__ prd, float* __restrict__ conv)
{
    __shared__ __bf16 As[3 * 64 * 64];      // 24 KB
    __shared__ __bf16 Bs[2 * 385 * 64];     // 96.25 KB

    const int t = threadIdx.x;
    const int y0 = blockIdx.x * 4;
    const int m0 = blockIdx.y * 64;
    const int mb = blockIdx.z;
    const int mod = mb >> 1;

    const __bf16* Am = Wt + (long)mod * (9 * 256 * 512);
    const __bf16* Xb = Xp + (long)mb * NPIX * 512;

    const int lane = t & 63, quad = lane >> 4, l15 = lane & 15, w = t >> 6;

    if (t < 16)
        *(f32x4*)((char*)Bs + (t >> 3) * 49280 + 49152 + (t & 7) * 16) = (f32x4)0.f;
    asm volatile("s_waitcnt lgkmcnt(0)" ::: "memory");

    auto stage_a = [&](int buf, int tap, int cc) {
#pragma unroll
        for (int k = 0; k < 2; ++k) {
            int r  = w * 16 + k * 8 + (lane >> 3);
            int sl = (lane & 7) ^ (r & 7);
            const __bf16* src = Am + (long)tap * 131072 + (long)(m0 + r) * 512
                              + cc * 64 + sl * 8;
            load_lds16(src, (char*)As + buf * 8192 + (w * 16 + k * 8) * 128);
        }
    };
    auto stage_b = [&](int buf, int cc) {
#pragma unroll
        for (int k = 0; k < 12; ++k) {
            int r  = w * 96 + k * 8 + (lane >> 3);
            int sl = (lane & 7) ^ (r & 7);
            int hr = r >> 6, xx = r & 63;
            int gy = y0 + hr - 1;
            const __bf16* src = ((unsigned)gy < 64u)
                ? Xb + (long)(gy * 64 + xx) * 512 + cc * 64 + sl * 8
                : zrow + sl * 8;
            load_lds16(src, (char*)Bs + buf * 49280 + (w * 96 + k * 8) * 128);
        }
    };

    f32x4 acc[4][4];
#pragma unroll
    for (int i = 0; i < 4; ++i)
#pragma unroll
        for (int j = 0; j < 4; ++j) acc[i][j] = (f32x4)0.f;

    stage_b(0, 0);
    stage_a(0, 0, 0);
    stage_a(1, 1, 0);

    const int soffA0 = ((quad ^ (l15 & 7)) << 4);
    const int soffA1 = (((4 | quad) ^ (l15 & 7)) << 4);

    for (int c = 0; c < 8; ++c) {
        for (int tp = 0; tp < 9; ++tp) {
            const int s = c * 9 + tp;
            if (s == 71)                  { asm volatile("s_waitcnt vmcnt(0)" ::: "memory"); }
            else if (tp >= 7 && c < 7)    { asm volatile("s_waitcnt vmcnt(14)" ::: "memory"); }
            else                          { asm volatile("s_waitcnt vmcnt(2)" ::: "memory"); }
            __builtin_amdgcn_sched_barrier(0);
            __builtin_amdgcn_s_barrier();
            __builtin_amdgcn_sched_barrier(0);

            if (s + 2 < 72) {
                int c2 = (tp + 2 >= 9) ? c + 1 : c;
                int t2 = (tp + 2 >= 9) ? tp - 7 : tp + 2;
                int b2 = (s + 2) % 3;
                stage_a(b2, t2, c2);
            }
            __builtin_amdgcn_sched_barrier(0);
            if (tp == 6 && c < 7) stage_b((c + 1) & 1, c + 1);
            __builtin_amdgcn_sched_barrier(0);

            const char* ab = (const char*)As + (s % 3) * 8192;
            const char* bb = (const char*)Bs + (c & 1) * 49280;
            const int dy = tp / 3 - 1, dx = tp % 3 - 1;
            const int hr = w + 1 + dy;
            int rb[4];
#pragma unroll
            for (int fj = 0; fj < 4; ++fj) {
                int x = fj * 16 + l15 + dx;
                rb[fj] = ((unsigned)x < 64u) ? hr * 64 + x : 384;
            }
#pragma unroll
            for (int kk = 0; kk < 2; ++kk) {
                const int slq = kk * 4 + quad;
                bf16x8 af[4], bfr[4];
#pragma unroll
                for (int i = 0; i < 4; ++i)
                    af[i] = *(const bf16x8*)(ab + (16 * i + l15) * 128
                                             + (kk ? soffA1 : soffA0));
#pragma unroll
                for (int fj = 0; fj < 4; ++fj)
                    bfr[fj] = *(const bf16x8*)(bb + rb[fj] * 128
                                               + ((slq ^ (rb[fj] & 7)) << 4));
#pragma unroll
                for (int i = 0; i < 4; ++i)
#pragma unroll
                    for (int fj = 0; fj < 4; ++fj)
                        acc[i][fj] = __builtin_amdgcn_mfma_f32_16x16x32_bf16(
                            af[i], bfr[fj], acc[i][fj], 0, 0, 0);
            }
        }
    }

    const float alpha = (mod ? prd : prr)[0];
    float* outp = conv + (long)mb * 256 * NPIX;
    const int nbase = (y0 + w) * 64;
#pragma unroll
    for (int i = 0; i < 4; ++i) {
#pragma unroll
        for (int r = 0; r < 4; ++r) {
            int oc = m0 + 16 * i + quad * 4 + r;
            float sc = scA[mod * 256 + oc];
            float sh = shB[mod * 256 + oc];
            float* orow = outp + (long)oc * NPIX;
#pragma unroll
            for (int fj = 0; fj < 4; ++fj) {
                int n = nbase + 16 * fj + l15;
                float y = acc[i][fj][r] * sc + sh;
                y = (y > 0.f) ? y : alpha * y;
                orow[n] = y;
            }
        }
    }
}

// ---------------------------------------------------------------------------
// 1x1-projection MFMA GEMM. mode 0 output scaled by oscale (log2e for Q).
// ---------------------------------------------------------------------------
__global__ __launch_bounds__(256)
void proj_mfma(const __bf16* __restrict__ Wb, int mstride,
               const __bf16* __restrict__ Bt,
               const float* __restrict__ bias_r, const float* __restrict__ bias_d,
               __bf16* __restrict__ dstT, __bf16* __restrict__ dstV,
               float* __restrict__ dstU,
               const float* __restrict__ resid_r, const float* __restrict__ resid_d,
               int mode, float oscale)
{
    __shared__ __bf16 As[128 * 32];
    __shared__ __bf16 Bs[128 * 32];

    const int t = threadIdx.x;
    const int n0 = blockIdx.x * 128;
    const int m0 = blockIdx.y * 128;
    const int mb = blockIdx.z;
    const int mod = mb >> 1, b = mb & 1;

    const __bf16* Am = Wb + (long)mod * mstride;
    const __bf16* Bm = Bt + (long)mb * (NPIX * 256);
    const float* bias = mod ? bias_d : bias_r;

    const int rowa = t >> 2, c16 = t & 3;
    char* ldsA0 = (char*)As + (t >> 6) * 1024;
    char* ldsA1 = ldsA0 + 4096;
    char* ldsB0 = (char*)Bs + (t >> 6) * 1024;
    char* ldsB1 = ldsB0 + 4096;
    const __bf16* srcA = Am + (long)(m0 + rowa) * 256 + c16 * 8;
    const __bf16* srcB = Bm + (long)(n0 + rowa) * 256 + c16 * 8;

    const int lane = t & 63, quad = lane >> 4, l15 = lane & 15, w = t >> 6;
    const int mw = (w >> 1) * 64, nw = (w & 1) * 64;
    const char* abase = (const char*)As + (mw + l15) * 64 + quad * 16;
    const char* bbase = (const char*)Bs + (nw + l15) * 64 + quad * 16;

    f32x4 acc[4][4];
#pragma unroll
    for (int i = 0; i < 4; ++i)
#pragma unroll
        for (int j = 0; j < 4; ++j) acc[i][j] = (f32x4)0.f;

    for (int kc = 0; kc < 256; kc += 32) {
        load_lds16(srcA + kc, ldsA0);
        load_lds16(srcA + kc + 16384, ldsA1);
        load_lds16(srcB + kc, ldsB0);
        load_lds16(srcB + kc + 16384, ldsB1);
        __syncthreads();

        bf16x8 af[4], bfr[4];
#pragma unroll
        for (int i = 0; i < 4; ++i) af[i]  = *(const bf16x8*)(abase + i * 1024);
#pragma unroll
        for (int j = 0; j < 4; ++j) bfr[j] = *(const bf16x8*)(bbase + j * 1024);
#pragma unroll
        for (int i = 0; i < 4; ++i)
#pragma unroll
            for (int j = 0; j < 4; ++j)
                acc[i][j] = __builtin_amdgcn_mfma_f32_16x16x32_bf16(
                    af[i], bfr[j], acc[i][j], 0, 0, 0);
        __syncthreads();
    }

    if (mode == 0) {
        if (mw == 0) {
            __bf16* dbase = dstT + (long)mb * (NPIX * 32);
#pragma unroll
            for (int fi = 0; fi < 2; ++fi)
#pragma unroll
                for (int r = 0; r < 4; ++r) {
                    int oc = 16 * fi + quad * 4 + r;
                    float bi = bias[oc];
#pragma unroll
                    for (int fj = 0; fj < 4; ++fj) {
                        int n = n0 + nw + 16 * fj + l15;
                        dbase[(long)n * 32 + oc] = f2b((acc[fi][fj][r] + bi) * oscale);
                    }
                }
        }
    } else if (mode == 1) {
        __bf16* dv = dstV + (long)mb * (256 * NPIX);
#pragma unroll
        for (int fi = 0; fi < 4; ++fi)
#pragma unroll
            for (int r = 0; r < 4; ++r) {
                int c = m0 + mw + 16 * fi + quad * 4 + r;
                float bi = bias[c];
                __bf16* row = dv + (long)c * NPIX;
#pragma unroll
                for (int fj = 0; fj < 4; ++fj) {
                    int n = n0 + nw + 16 * fj + l15;
                    row[n] = f2b(acc[fi][fj][r] + bi);
                }
            }
    } else {
        float* du = dstU + (long)mod * 4194304 + (long)b * 2097152;
        const float* rs = (mod ? resid_d : resid_r) + (long)b * 2097152;
#pragma unroll
        for (int fi = 0; fi < 4; ++fi)
#pragma unroll
            for (int r = 0; r < 4; ++r) {
                int oc = m0 + mw + 16 * fi + quad * 4 + r;
                float bi = bias[oc];
                const float* rrow = rs + (long)oc * NPIX;
                float* orow = du + (long)oc * NPIX;
#pragma unroll
                for (int fj = 0; fj < 4; ++fj) {
                    int n = n0 + nw + 16 * fj + l15;
                    orow[n] = acc[fi][fj][r] + bi + rrow[n];
                }
            }
    }
}

// ---------------------------------------------------------------------------
// Online MFMA row stats over a j-SEGMENT [seg*1024, +1024): partial (m, l)
// in log2 domain, single pass. grid (32 i, 4 mbo, 4 seg) = 512 blocks.
// K/Q LDS slot-swizzled ^((row>>1)&3) (conflict-free reads).
// ---------------------------------------------------------------------------
__global__ __launch_bounds__(256)
void attn_stats_mfma(const __bf16* __restrict__ Qt, const __bf16* __restrict__ Kt,
                     float* __restrict__ rmp, float* __restrict__ rlp)
{
    __shared__ __bf16 Qs[128 * 32];
    __shared__ __bf16 Ks[128 * 32];
    __shared__ float redm[2][128];
    __shared__ float redl[2][128];

    const int t  = threadIdx.x;
    const int i0 = blockIdx.x * 128;
    const int mbo = blockIdx.y;
    const int o  = mbo >> 1, b = mbo & 1;
    const int seg = blockIdx.z;
    const int jbase = seg * 1024;
    const int mbK = o * 2 + b, mbQ = (1 - o) * 2 + b;

    const __bf16* Qg = Qt + (long)mbQ * 131072;
    const __bf16* Kg = Kt + (long)mbK * 131072;

    const int lane = t & 63, quad = lane >> 4, l15 = lane & 15, w = t >> 6;
    const int mS = (w >> 1) * 64;
    const int nS = (w & 1) * 64;

    const int drow = w * 16 + (lane >> 2);                  // staging dest row
    const int ssl  = ((lane & 3) ^ ((lane >> 3) & 3)) * 16; // swizzled src slot
    const int rsl  = (quad ^ ((l15 >> 1) & 3)) << 4;        // swizzled read slot

    load_lds16((const char*)Qg + (long)(i0 + drow) * 64 + ssl, (char*)Qs + w * 1024);
    load_lds16((const char*)Qg + (long)(i0 + 64 + drow) * 64 + ssl,
               (char*)Qs + 4096 + w * 1024);
    __syncthreads();

    bf16x8 qa[4];
#pragma unroll
    for (int fi = 0; fi < 4; ++fi)
        qa[fi] = *(const bf16x8*)((const char*)Qs + (mS + 16 * fi + l15) * 64 + rsl);

    const f32x4 zero4 = (f32x4)0.f;
    float m_t[16], l_t[16];
#pragma unroll
    for (int e = 0; e < 16; ++e) { m_t[e] = -3.0e38f; l_t[e] = 0.f; }

    for (int j0 = jbase; j0 < jbase + 1024; j0 += 128) {
        __syncthreads();
        load_lds16((const char*)Kg + (long)(j0 + drow) * 64 + ssl, (char*)Ks + w * 1024);
        load_lds16((const char*)Kg + (long)(j0 + 64 + drow) * 64 + ssl,
                   (char*)Ks + 4096 + w * 1024);
        __syncthreads();

        bf16x8 kb[4];
#pragma unroll
        for (int fj = 0; fj < 4; ++fj)
            kb[fj] = *(const bf16x8*)((const char*)Ks + (nS + 16 * fj + l15) * 64 + rsl);
#pragma unroll
        for (int fi = 0; fi < 4; ++fi) {
            f32x4 sf[4];
#pragma unroll
            for (int fj = 0; fj < 4; ++fj)
                sf[fj] = __builtin_amdgcn_mfma_f32_16x16x32_bf16(qa[fi], kb[fj], zero4, 0, 0, 0);
#pragma unroll
            for (int r = 0; r < 4; ++r) {
                int e = fi * 4 + r;
                float a = fmaxf(fmaxf(sf[0][r], sf[1][r]), fmaxf(sf[2][r], sf[3][r]));
                float nm = fmaxf(m_t[e], a);
                float s = exp2f(sf[0][r] - nm) + exp2f(sf[1][r] - nm)
                        + exp2f(sf[2][r] - nm) + exp2f(sf[3][r] - nm);
                l_t[e] = l_t[e] * exp2f(m_t[e] - nm) + s;
                m_t[e] = nm;
            }
        }
    }

#pragma unroll
    for (int d = 1; d < 16; d <<= 1)
#pragma unroll
        for (int e = 0; e < 16; ++e) {
            float om = __shfl_xor(m_t[e], d, 64);
            float ol = __shfl_xor(l_t[e], d, 64);
            float nm = fmaxf(m_t[e], om);
            l_t[e] = l_t[e] * exp2f(m_t[e] - nm) + ol * exp2f(om - nm);
            m_t[e] = nm;
        }
    if (l15 == 0) {
#pragma unroll
        for (int fi = 0; fi < 4; ++fi)
#pragma unroll
            for (int r = 0; r < 4; ++r) {
                redm[w & 1][mS + 16 * fi + quad * 4 + r] = m_t[fi * 4 + r];
                redl[w & 1][mS + 16 * fi + quad * 4 + r] = l_t[fi * 4 + r];
            }
    }
    __syncthreads();
    if (t < 128) {
        float m0 = redm[0][t], m1 = redm[1][t];
        float l0 = redl[0][t], l1 = redl[1][t];
        float m = fmaxf(m0, m1);
        float l = l0 * exp2f(m0 - m) + l1 * exp2f(m1 - m);
        rmp[seg * 16384 + mbo * 4096 + i0 + t] = m;
        rlp[seg * 16384 + mbo * 4096 + i0 + t] = l;
    }
}

// ---------------------------------------------------------------------------
// Merge 4-segment stats: m = max, rl = 1/sum(l_s * 2^(m_s-m)). grid 64x256.
// ---------------------------------------------------------------------------
__global__ __launch_bounds__(256)
void stats_merge(const float* __restrict__ rmp, const float* __restrict__ rlp,
                 float* __restrict__ rmb, float* __restrict__ rlb)
{
    int idx = blockIdx.x * 256 + threadIdx.x;
    float m = rmp[idx];
#pragma unroll
    for (int s = 1; s < 4; ++s) m = fmaxf(m, rmp[s * 16384 + idx]);
    float l = 0.f;
#pragma unroll
    for (int s = 0; s < 4; ++s)
        l += rlp[s * 16384 + idx] * exp2f(rmp[s * 16384 + idx] - m);
    rmb[idx] = m;
    rlb[idx] = 1.f / l;
}

// ---------------------------------------------------------------------------
// Fused MFMA PV v3. i-tile 128, c=256, j-seg 2048 (32 steps of 64).
// Linear grid 256 = 1 block/CU; bx&7 = (mb<<1)|seg -> XCD-grouped so the 32
// i-blocks sharing one 1MB V-slice live on one XCD (V/K L2-resident).
// 3-buffer K/V counted-vmcnt pipeline; 2-buffer P. 148KB LDS, 256 threads.
// Wave w: S rows [32w,32w+32), PV c rows [64w,64w+64), acc 4x8 over i=128.
// Slot swizzles: V/K/Q phys slot = logical ^ ((row>>1)&3) (inverse applied
// to global src; global_load_lds dest stays linear); P byte ^= (il&7)<<4.
// ---------------------------------------------------------------------------
__global__ __launch_bounds__(256, 1)
void attn_pv_mfma(const __bf16* __restrict__ Qt, const __bf16* __restrict__ Kt,
                  const __bf16* __restrict__ Vb,
                  float* __restrict__ part0, float* __restrict__ part1,
                  const float* __restrict__ rmb, const float* __restrict__ rlb)
{
    __shared__ __bf16 Qs[128 * 32];          // 8KB   [128 i][32ch]
    __shared__ __bf16 Ks[3 * 64 * 32];       // 12KB  3 bufs [64 j][32ch]
    __shared__ __bf16 Vs[3 * 2 * 256 * 32];  // 96KB  3 bufs [2ks][256c][32j]
    __shared__ __bf16 Ps[2 * 128 * 64];      // 32KB  2 bufs [128 i][64 j]

    const int t  = threadIdx.x;
    const int bx = blockIdx.x;
    const int grp = bx & 7;                  // XCD group = (mb<<1)|seg
    const int i0  = (bx >> 3) * 128;
    const int seg = grp & 1;
    const int mb  = grp >> 1;
    const int o  = mb >> 1, b = mb & 1;
    const int mbQ = (1 - o) * 2 + b;
    const int jbase = seg * 2048;

    const __bf16* Qg = Qt + (long)mbQ * 131072;
    const __bf16* Kg = Kt + (long)mb * 131072;
    const __bf16* Vg = Vb + (long)mb * 1048576;
    const float* rm = rmb + mb * 4096;
    const float* rl = rlb + mb * 4096;

    const int lane = t & 63, quad = lane >> 4, l15 = lane & 15, w = t >> 6;
    const int iw = w * 32;                   // S row block
    const int cw = w * 64;                   // PV c block

    const int drow = w * 16 + (lane >> 2);                  // staging dest row
    const int ssl  = ((lane & 3) ^ ((lane >> 3) & 3)) * 16; // swizzled src slot
    const int rsl  = (quad ^ ((l15 >> 1) & 3)) << 4;        // swizzled read slot

    // m/l loads — completed before any staging so vmcnt counts stay exact
    float mlv[8], rlv[8];
#pragma unroll
    for (int fi = 0; fi < 2; ++fi)
#pragma unroll
        for (int r = 0; r < 4; ++r)
            mlv[fi * 4 + r] = rm[i0 + iw + 16 * fi + quad * 4 + r];
#pragma unroll
    for (int fj = 0; fj < 8; ++fj) rlv[fj] = rl[i0 + 16 * fj + l15];
    asm volatile("s_waitcnt vmcnt(0)" ::: "memory");

    // Q stage + fragment read (once)
    load_lds16((const char*)Qg + (long)(i0 + drow) * 64 + ssl, (char*)Qs + w * 1024);
    load_lds16((const char*)Qg + (long)(i0 + 64 + drow) * 64 + ssl,
               (char*)Qs + 4096 + w * 1024);
    asm volatile("s_waitcnt vmcnt(0)" ::: "memory");
    __builtin_amdgcn_s_barrier();
    bf16x8 qa[2];
    qa[0] = *(const bf16x8*)((const char*)Qs + (iw + l15) * 64 + rsl);
    qa[1] = *(const bf16x8*)((const char*)Qs + (iw + 16 + l15) * 64 + rsl);

    // 9 loads per thread per step: 1 K + 8 V
    auto stage = [&](int sidx) {
        const int buf = sidx % 3;
        const int j0 = jbase + sidx * 64;
        load_lds16((const char*)Kg + (long)(j0 + drow) * 64 + ssl,
                   (char*)Ks + buf * 4096 + w * 1024);
#pragma unroll
        for (int ii = 0; ii < 8; ++ii) {
            int ks = ii >> 2;
            int c  = (ii & 3) * 64 + drow;
            load_lds16((const char*)Vg + (long)c * 8192 + (long)(j0 + ks * 32) * 2 + ssl,
                       (char*)Vs + buf * 32768 + ii * 4096 + w * 1024);
        }
    };

    f32x4 acc[4][8];
#pragma unroll
    for (int i = 0; i < 4; ++i)
#pragma unroll
        for (int j = 0; j < 8; ++j) acc[i][j] = (f32x4)0.f;
    const f32x4 zero4 = (f32x4)0.f;

    stage(0);

    for (int s = 0; s < 32; ++s) {
        if (s + 1 < 32) {
            stage(s + 1);
            asm volatile("s_waitcnt vmcnt(9)" ::: "memory");   // stage(s) done
        } else {
            asm volatile("s_waitcnt vmcnt(0)" ::: "memory");
        }
        __builtin_amdgcn_sched_barrier(0);
        __builtin_amdgcn_s_barrier();                          // K/V(s) ready all
        __builtin_amdgcn_sched_barrier(0);

        // S = Q K^T  (8 MFMA), P = exp2(S - m) -> Ps[s&1]
        const char* kbp = (const char*)Ks + (s % 3) * 4096;
        f32x4 sA[2][4];
#pragma unroll
        for (int fj = 0; fj < 4; ++fj) {
            bf16x8 kb = *(const bf16x8*)(kbp + (16 * fj + l15) * 64 + rsl);
            sA[0][fj] = __builtin_amdgcn_mfma_f32_16x16x32_bf16(qa[0], kb, zero4, 0, 0, 0);
            sA[1][fj] = __builtin_amdgcn_mfma_f32_16x16x32_bf16(qa[1], kb, zero4, 0, 0, 0);
        }
        char* pst = (char*)Ps + (s & 1) * 16384;
#pragma unroll
        for (int fi = 0; fi < 2; ++fi)
#pragma unroll
            for (int fj = 0; fj < 4; ++fj)
#pragma unroll
                for (int r = 0; r < 4; ++r) {
                    int il = iw + 16 * fi + quad * 4 + r;
                    int boff = (il * 128 + (16 * fj + l15) * 2) ^ ((il & 7) << 4);
                    *(__bf16*)(pst + boff) = f2b(exp2f(sA[fi][fj][r] - mlv[fi * 4 + r]));
                }
        __builtin_amdgcn_sched_barrier(0);
        __builtin_amdgcn_s_barrier();                          // P(s) visible
        __builtin_amdgcn_sched_barrier(0);

        // PV: acc += V P^T  (64 MFMA)
        const char* vbp = (const char*)Vs + (s % 3) * 32768;
        const char* prd = (const char*)Ps + (s & 1) * 16384;
#pragma unroll
        for (int ks = 0; ks < 2; ++ks) {
            bf16x8 va[4], pb[8];
#pragma unroll
            for (int fi = 0; fi < 4; ++fi)
                va[fi] = *(const bf16x8*)(vbp + ks * 16384 +
                                          (cw + 16 * fi + l15) * 64 + rsl);
#pragma unroll
            for (int fj = 0; fj < 8; ++fj) {
                int ip = 16 * fj + l15;
                int boff = (ip * 128 + ks * 64 + quad * 16) ^ ((ip & 7) << 4);
                pb[fj] = *(const bf16x8*)(prd + boff);
            }
#pragma unroll
            for (int fi = 0; fi < 4; ++fi)
#pragma unroll
                for (int fj = 0; fj < 8; ++fj)
                    acc[fi][fj] = __builtin_amdgcn_mfma_f32_16x16x32_bf16(
                        va[fi], pb[fj], acc[fi][fj], 0, 0, 0);
        }
    }

    // partial store, rl folded (acc * 1/l)
    float* pg = (seg ? part1 : part0) + (long)mb * 1048576;
#pragma unroll
    for (int fi = 0; fi < 4; ++fi) {
#pragma unroll
        for (int r = 0; r < 4; ++r) {
            int c = cw + 16 * fi + quad * 4 + r;
            float* zr = pg + (long)c * 4096;
#pragma unroll
            for (int fj = 0; fj < 8; ++fj)
                zr[i0 + 16 * fj + l15] = acc[fi][fj][r] * rlv[fj];
        }
    }
}

// ---------------------------------------------------------------------------
// z = gamma*(part0+part1) + conv, transposed bf16 store to Zt[pix][256].
// grid (128, 8, 4).
// ---------------------------------------------------------------------------
__global__ __launch_bounds__(256)
void zred_t(const float* __restrict__ p0, const float* __restrict__ p1,
            const float* __restrict__ convb, __bf16* __restrict__ Zt,
            const float* __restrict__ g_r, const float* __restrict__ g_d)
{
    __shared__ float tile[32][33];
    const int t = threadIdx.x;
    const int pix0 = blockIdx.x * 32;
    const int c0 = blockIdx.y * 32;
    const int mb = blockIdx.z;
    const int o = mb >> 1;
    const float gamma = (o ? g_d : g_r)[0];
    const long base = (long)mb * 1048576;

    int i = t >> 3, j4 = (t & 7) * 4;
    long row = base + (long)(c0 + i) * 4096 + pix0 + j4;
    float4 a = *(const float4*)&p0[row];
    float4 b = *(const float4*)&p1[row];
    float4 cv = *(const float4*)&convb[row];
    tile[i][j4 + 0] = gamma * (a.x + b.x) + cv.x;
    tile[i][j4 + 1] = gamma * (a.y + b.y) + cv.y;
    tile[i][j4 + 2] = gamma * (a.z + b.z) + cv.z;
    tile[i][j4 + 3] = gamma * (a.w + b.w) + cv.w;
    __syncthreads();
    int j = t >> 3, i4 = (t & 7) * 4;
    bf16x4 oq;
    oq.x = f2b(tile[i4 + 0][j]); oq.y = f2b(tile[i4 + 1][j]);
    oq.z = f2b(tile[i4 + 2][j]); oq.w = f2b(tile[i4 + 3][j]);
    *(bf16x4*)&Zt[(long)mb * NPIX * 256 + (long)(pix0 + j) * 256 + c0 + i4] = oq;
}

// ---------------------------------------------------------------------------
// Host launcher (ws layout unchanged — see round 10 comment)
// ---------------------------------------------------------------------------
extern "C" void kernel_launch(void* const* d_in, const int* in_sizes, int n_in,
                              void* d_out, int out_size, void* d_ws, size_t ws_size,
                              hipStream_t stream)
{
    const float* in_rgb = (const float*)d_in[0];
    const float* in_dsm = (const float*)d_in[1];
    auto P = [&](int i) { return (const float*)d_in[i]; };

    float* ws    = (float*)d_ws;
    float* conv  = ws;
    float* part0 = ws + 4194304;
    float* rmb   = ws + 8388608;
    float* rlb   = ws + 8404992;
    float* rmp   = part0;            // [4][4][4096] scratch, dead before pv
    float* rlp   = part0 + 65536;
    float* scA   = ws + 8486912;
    float* shB   = ws + 8487424;
    __bf16* zrow = (__bf16*)(ws + 8487936);
    __bf16* Wt   = (__bf16*)(ws + 8488192);
    __bf16* Xp   = (__bf16*)(ws + 9667840);
    float*  part1 = ws + 9667840;            // aliases Xp (dead after conv)
    __bf16* Qt   = (__bf16*)(ws + 13862144);
    __bf16* Kt   = (__bf16*)(ws + 14124288);
    __bf16* Vbb  = (__bf16*)(ws + 14386432);
    __bf16* Ct   = (__bf16*)(ws + 16483584);
    __bf16* Zt   = (__bf16*)(ws + 18580736);
    __bf16* Wq   = (__bf16*)(ws + 20677888);
    __bf16* Wk   = (__bf16*)(ws + 20710656);
    __bf16* Wv   = (__bf16*)(ws + 20743424);
    __bf16* Wu   = (__bf16*)(ws + 20808960);

    // prep
    prep_w<<<2307, 256, 0, stream>>>(
        P(2), P(18), P(3), P(4), P(5), P(6), P(7),
        P(19), P(20), P(21), P(22), P(23),
        Wt, scA, shB, zrow);
    prep_gw<<<512, 256, 0, stream>>>(
        P(9), P(25), P(11), P(27), P(13), P(29), P(15), P(31),
        Wq, Wk, Wv, Wu);
    xpose<<<dim3(128, 16, 4), 256, 0, stream>>>(in_rgb, in_dsm, Xp);

    // conv3x3 + BN + PReLU (v3: halo, 256 blocks = 1/CU, counted vmcnt)
    conv_mfma<<<dim3(16, 4, 4), 256, 0, stream>>>(
        Wt, Xp, zrow, scA, shB, P(8), P(24), conv);
    t256<<<dim3(128, 8, 4), 256, 0, stream>>>(conv, Ct);

    // q/k/v projections (Q pre-scaled by log2e -> exp2 softmax domain)
    proj_mfma<<<dim3(32, 1, 4), 256, 0, stream>>>(
        Wq, 32768, Ct, P(10), P(26), Qt, nullptr, nullptr, nullptr, nullptr,
        0, 1.4426950408889634f);
    proj_mfma<<<dim3(32, 1, 4), 256, 0, stream>>>(
        Wk, 32768, Ct, P(12), P(28), Kt, nullptr, nullptr, nullptr, nullptr,
        0, 1.0f);
    proj_mfma<<<dim3(32, 2, 4), 256, 0, stream>>>(
        Wv, 65536, Ct, P(14), P(30), nullptr, Vbb, nullptr, nullptr, nullptr,
        1, 1.0f);

    // online softmax stats (j-split x4, 512 blocks) + merge
    attn_stats_mfma<<<dim3(32, 4, 4), 256, 0, stream>>>(Qt, Kt, rmp, rlp);
    stats_merge<<<64, 256, 0, stream>>>(rmp, rlp, rmb, rlb);

    // fused PV v3 (linear grid 256, XCD-grouped; part1 overwrites dead Xp)
    attn_pv_mfma<<<256, 256, 0, stream>>>(
        Qt, Kt, Vbb, part0, part1, rmb, rlb);

    // z = gamma*(p0+p1)+conv, transpose + bf16 -> Zt
    zred_t<<<dim3(128, 8, 4), 256, 0, stream>>>(
        part0, part1, conv, Zt, P(17), P(33));

    // up projection + input residual -> fp32 out
    proj_mfma<<<dim3(32, 4, 4), 256, 0, stream>>>(
        Wu, 131072, Zt, P(16), P(32), nullptr, nullptr, (float*)d_out,
        in_rgb, in_dsm, 2, 1.0f);
}

// Round 5
// 363.492 us; speedup vs baseline: 1.0288x; 1.0288x over previous
//
#include <hip/hip_runtime.h>
#include <hip/hip_bf16.h>
#include <stdint.h>

// fp32 I/O. Conv3x3, 1x1 projections, and attention run as bf16 MFMA.
// Softmax stats (m,l) and P come from the SAME bf16 MFMA S path (unscaled
// attention -> near-argmax softmax; any S mismatch scales o by exp(dS)).
// Round 10: conv halo restructure (staged traffic 885->245MB).
// Round 11: pv i128/1-block-per-CU: conflicts->0, FETCH 37->5.9MB (both fixes
//   WORKED) but occupancy 10% (1 wave/SIMD) exposed all latency -> 79us.
// Round 12 (this): pv v4 = round-3's 2-blocks/CU structure (i64, 48KB LDS,
//   512 blocks, 8 waves/CU) + round-11's verified fixes:
//   - conflict-free slot swizzles (ssl staging / rsl read, P (il&7)<<4);
//   - XCD grouping bx&7=(mb<<1)|seg -> V/K L2-resident.
//   LDS floor ~28us, L2 V-staging ~16us overlapped -> predict ~40us.

constexpr int CINCH = 512;
constexpr int NPIX  = 4096;   // 64*64

typedef __bf16 bf16x8 __attribute__((ext_vector_type(8)));
typedef __bf16 bf16x4 __attribute__((ext_vector_type(4)));
typedef float  f32x4  __attribute__((ext_vector_type(4)));

__device__ __forceinline__ __bf16 f2b(float f) {
    __hip_bfloat16 h = __float2bfloat16(f);
    return *reinterpret_cast<__bf16*>(&h);
}

__device__ __forceinline__ void load_lds16(const void* g, void* l) {
    __builtin_amdgcn_global_load_lds(
        (const __attribute__((address_space(1))) unsigned int*)(uintptr_t)g,
        (__attribute__((address_space(3))) unsigned int*)(uintptr_t)l,
        16, 0, 0);
}

// ---------------------------------------------------------------------------
// Prep A: conv weights fp32 [oc][ic][9] -> Wt bf16 [mod][tap][oc][ic];
// BN scale/shift tables; zero row. grid 2307 x 256.
// ---------------------------------------------------------------------------
__global__ __launch_bounds__(256)
void prep_w(const float* __restrict__ w_r, const float* __restrict__ w_d,
            const float* __restrict__ cb_r, const float* __restrict__ bg_r,
            const float* __restrict__ bb_r, const float* __restrict__ bm_r,
            const float* __restrict__ bv_r,
            const float* __restrict__ cb_d, const float* __restrict__ bg_d,
            const float* __restrict__ bb_d, const float* __restrict__ bm_d,
            const float* __restrict__ bv_d,
            __bf16* __restrict__ Wt, float* __restrict__ scA,
            float* __restrict__ shB, __bf16* __restrict__ zrow)
{
    const int t = threadIdx.x;
    const int blk = blockIdx.x;
    if (blk < 2304) {
        int gid = blk * 1024 + t * 4;
        int mod = gid >= 1179648;
        int o2  = gid - mod * 1179648;
        int tap = o2 >> 17;
        int r   = o2 & 131071;
        int oc  = r >> 9;
        int ic  = r & 511;
        const float* wsrc = mod ? w_d : w_r;
        long base = ((long)(oc * 512 + ic)) * 9 + tap;
        bf16x4 v;
        v.x = f2b(wsrc[base]);
        v.y = f2b(wsrc[base + 9]);
        v.z = f2b(wsrc[base + 18]);
        v.w = f2b(wsrc[base + 27]);
        *(bf16x4*)&Wt[gid] = v;
    } else if (blk == 2304) {
        unsigned short* z = (unsigned short*)zrow;
        z[t] = 0; z[t + 256] = 0;
    } else {
        int mod = blk - 2305;
        const float* cb = mod ? cb_d : cb_r;
        const float* bg = mod ? bg_d : bg_r;
        const float* bb = mod ? bb_d : bb_r;
        const float* bm = mod ? bm_d : bm_r;
        const float* bv = mod ? bv_d : bv_r;
        int oc = t;
        float sc = bg[oc] * rsqrtf(bv[oc] + 1e-5f);
        scA[mod * 256 + oc] = sc;
        shB[mod * 256 + oc] = (cb[oc] - bm[oc]) * sc + bb[oc];
    }
}

// ---------------------------------------------------------------------------
// Prep B: projection weights fp32 -> bf16. Wq/Wk padded to 128 rows (zeros).
// ---------------------------------------------------------------------------
__global__ __launch_bounds__(256)
void prep_gw(const float* __restrict__ qw_r, const float* __restrict__ qw_d,
             const float* __restrict__ kw_r, const float* __restrict__ kw_d,
             const float* __restrict__ vw_r, const float* __restrict__ vw_d,
             const float* __restrict__ uw_r, const float* __restrict__ uw_d,
             __bf16* __restrict__ Wq, __bf16* __restrict__ Wk,
             __bf16* __restrict__ Wv, __bf16* __restrict__ Wu)
{
    int gid = blockIdx.x * 1024 + threadIdx.x * 4;
    __bf16* dst;
    float4 f = make_float4(0.f, 0.f, 0.f, 0.f);
    if (gid < 65536) {
        int mod = gid >> 15, e = gid & 32767;
        dst = Wq + gid;
        if (e < 8192) f = *(const float4*)((mod ? qw_d : qw_r) + e);
    } else if (gid < 131072) {
        int g = gid - 65536;
        int mod = g >> 15, e = g & 32767;
        dst = Wk + g;
        if (e < 8192) f = *(const float4*)((mod ? kw_d : kw_r) + e);
    } else if (gid < 262144) {
        int g = gid - 131072;
        int mod = g >> 16, e = g & 65535;
        dst = Wv + g;
        f = *(const float4*)((mod ? vw_d : vw_r) + e);
    } else {
        int g = gid - 262144;
        int mod = g >> 17, e = g & 131071;
        dst = Wu + g;
        f = *(const float4*)((mod ? uw_d : uw_r) + e);
    }
    bf16x4 o; o.x = f2b(f.x); o.y = f2b(f.y); o.z = f2b(f.z); o.w = f2b(f.w);
    *(bf16x4*)dst = o;
}

// ---------------------------------------------------------------------------
// Prep C: X fp32 [mod][b][512][4096] -> Xp bf16 [modb][4096pix][512ic]
// ---------------------------------------------------------------------------
__global__ __launch_bounds__(256)
void xpose(const float* __restrict__ inr, const float* __restrict__ ind,
           __bf16* __restrict__ Xp)
{
    __shared__ float tile[32][33];
    const int t = threadIdx.x;
    const int p0 = blockIdx.x * 32;
    const int ic0 = blockIdx.y * 32;
    const int mb = blockIdx.z;
    const int mod = mb >> 1, b = mb & 1;
    const float* src = (mod ? ind : inr) + (long)b * CINCH * NPIX;

    int i = t >> 3, j4 = (t & 7) * 4;
    float4 v = *(const float4*)&src[(long)(ic0 + i) * NPIX + p0 + j4];
    tile[i][j4 + 0] = v.x; tile[i][j4 + 1] = v.y;
    tile[i][j4 + 2] = v.z; tile[i][j4 + 3] = v.w;
    __syncthreads();
    int j = t >> 3, i4 = (t & 7) * 4;
    bf16x4 o;
    o.x = f2b(tile[i4 + 0][j]);
    o.y = f2b(tile[i4 + 1][j]);
    o.z = f2b(tile[i4 + 2][j]);
    o.w = f2b(tile[i4 + 3][j]);
    *(bf16x4*)&Xp[((long)mb * NPIX + p0 + j) * 512 + ic0 + i4] = o;
}

// ---------------------------------------------------------------------------
// fp32 [mb][256][4096] -> bf16 transposed [mb][4096][256]. grid (128, 8, 4).
// ---------------------------------------------------------------------------
__global__ __launch_bounds__(256)
void t256(const float* __restrict__ src, __bf16* __restrict__ dst)
{
    __shared__ float tile[32][33];
    const int t = threadIdx.x;
    const int p0 = blockIdx.x * 32;
    const int c0 = blockIdx.y * 32;
    const int mb = blockIdx.z;
    const float* s = src + (long)mb * 256 * NPIX;
    __bf16* d = dst + (long)mb * NPIX * 256;

    int i = t >> 3, j4 = (t & 7) * 4;
    float4 v = *(const float4*)&s[(long)(c0 + i) * NPIX + p0 + j4];
    tile[i][j4 + 0] = v.x; tile[i][j4 + 1] = v.y;
    tile[i][j4 + 2] = v.z; tile[i][j4 + 3] = v.w;
    __syncthreads();
    int j = t >> 3, i4 = (t & 7) * 4;
    bf16x4 o;
    o.x = f2b(tile[i4 + 0][j]); o.y = f2b(tile[i4 + 1][j]);
    o.z = f2b(tile[i4 + 2][j]); o.w = f2b(tile[i4 + 3][j]);
    *(bf16x4*)&d[((long)(p0 + j)) * 256 + c0 + i4] = o;
}

// ---------------------------------------------------------------------------
// Conv3x3 implicit-GEMM MFMA v3 (halo). Unchanged from round 10.
// ---------------------------------------------------------------------------
__global__ __launch_bounds__(256)
void conv_mfma(const __bf16* __restrict__ Wt, const __bf16* __restrict__ Xp,
               const __bf16* __restrict__ zrow, const float* __restrict__ scA,
               const float* __restrict__ shB, const float* __restrict__ prr,
               const float* __restrict__ prd, float* __restrict__ conv)
{
    __shared__ __bf16 As[3 * 64 * 64];      // 24 KB
    __shared__ __bf16 Bs[2 * 385 * 64];     // 96.25 KB

    const int t = threadIdx.x;
    const int y0 = blockIdx.x * 4;
    const int m0 = blockIdx.y * 64;
    const int mb = blockIdx.z;
    const int mod = mb >> 1;

    const __bf16* Am = Wt + (long)mod * (9 * 256 * 512);
    const __bf16* Xb = Xp + (long)mb * NPIX * 512;

    const int lane = t & 63, quad = lane >> 4, l15 = lane & 15, w = t >> 6;

    if (t < 16)
        *(f32x4*)((char*)Bs + (t >> 3) * 49280 + 49152 + (t & 7) * 16) = (f32x4)0.f;
    asm volatile("s_waitcnt lgkmcnt(0)" ::: "memory");

    auto stage_a = [&](int buf, int tap, int cc) {
#pragma unroll
        for (int k = 0; k < 2; ++k) {
            int r  = w * 16 + k * 8 + (lane >> 3);
            int sl = (lane & 7) ^ (r & 7);
            const __bf16* src = Am + (long)tap * 131072 + (long)(m0 + r) * 512
                              + cc * 64 + sl * 8;
            load_lds16(src, (char*)As + buf * 8192 + (w * 16 + k * 8) * 128);
        }
    };
    auto stage_b = [&](int buf, int cc) {
#pragma unroll
        for (int k = 0; k < 12; ++k) {
            int r  = w * 96 + k * 8 + (lane >> 3);
            int sl = (lane & 7) ^ (r & 7);
            int hr = r >> 6, xx = r & 63;
            int gy = y0 + hr - 1;
            const __bf16* src = ((unsigned)gy < 64u)
                ? Xb + (long)(gy * 64 + xx) * 512 + cc * 64 + sl * 8
                : zrow + sl * 8;
            load_lds16(src, (char*)Bs + buf * 49280 + (w * 96 + k * 8) * 128);
        }
    };

    f32x4 acc[4][4];
#pragma unroll
    for (int i = 0; i < 4; ++i)
#pragma unroll
        for (int j = 0; j < 4; ++j) acc[i][j] = (f32x4)0.f;

    stage_b(0, 0);
    stage_a(0, 0, 0);
    stage_a(1, 1, 0);

    const int soffA0 = ((quad ^ (l15 & 7)) << 4);
    const int soffA1 = (((4 | quad) ^ (l15 & 7)) << 4);

    for (int c = 0; c < 8; ++c) {
        for (int tp = 0; tp < 9; ++tp) {
            const int s = c * 9 + tp;
            if (s == 71)                  { asm volatile("s_waitcnt vmcnt(0)" ::: "memory"); }
            else if (tp >= 7 && c < 7)    { asm volatile("s_waitcnt vmcnt(14)" ::: "memory"); }
            else                          { asm volatile("s_waitcnt vmcnt(2)" ::: "memory"); }
            __builtin_amdgcn_sched_barrier(0);
            __builtin_amdgcn_s_barrier();
            __builtin_amdgcn_sched_barrier(0);

            if (s + 2 < 72) {
                int c2 = (tp + 2 >= 9) ? c + 1 : c;
                int t2 = (tp + 2 >= 9) ? tp - 7 : tp + 2;
                int b2 = (s + 2) % 3;
                stage_a(b2, t2, c2);
            }
            __builtin_amdgcn_sched_barrier(0);
            if (tp == 6 && c < 7) stage_b((c + 1) & 1, c + 1);
            __builtin_amdgcn_sched_barrier(0);

            const char* ab = (const char*)As + (s % 3) * 8192;
            const char* bb = (const char*)Bs + (c & 1) * 49280;
            const int dy = tp / 3 - 1, dx = tp % 3 - 1;
            const int hr = w + 1 + dy;
            int rb[4];
#pragma unroll
            for (int fj = 0; fj < 4; ++fj) {
                int x = fj * 16 + l15 + dx;
                rb[fj] = ((unsigned)x < 64u) ? hr * 64 + x : 384;
            }
#pragma unroll
            for (int kk = 0; kk < 2; ++kk) {
                const int slq = kk * 4 + quad;
                bf16x8 af[4], bfr[4];
#pragma unroll
                for (int i = 0; i < 4; ++i)
                    af[i] = *(const bf16x8*)(ab + (16 * i + l15) * 128
                                             + (kk ? soffA1 : soffA0));
#pragma unroll
                for (int fj = 0; fj < 4; ++fj)
                    bfr[fj] = *(const bf16x8*)(bb + rb[fj] * 128
                                               + ((slq ^ (rb[fj] & 7)) << 4));
#pragma unroll
                for (int i = 0; i < 4; ++i)
#pragma unroll
                    for (int fj = 0; fj < 4; ++fj)
                        acc[i][fj] = __builtin_amdgcn_mfma_f32_16x16x32_bf16(
                            af[i], bfr[fj], acc[i][fj], 0, 0, 0);
            }
        }
    }

    const float alpha = (mod ? prd : prr)[0];
    float* outp = conv + (long)mb * 256 * NPIX;
    const int nbase = (y0 + w) * 64;
#pragma unroll
    for (int i = 0; i < 4; ++i) {
#pragma unroll
        for (int r = 0; r < 4; ++r) {
            int oc = m0 + 16 * i + quad * 4 + r;
            float sc = scA[mod * 256 + oc];
            float sh = shB[mod * 256 + oc];
            float* orow = outp + (long)oc * NPIX;
#pragma unroll
            for (int fj = 0; fj < 4; ++fj) {
                int n = nbase + 16 * fj + l15;
                float y = acc[i][fj][r] * sc + sh;
                y = (y > 0.f) ? y : alpha * y;
                orow[n] = y;
            }
        }
    }
}

// ---------------------------------------------------------------------------
// 1x1-projection MFMA GEMM. mode 0 output scaled by oscale (log2e for Q).
// ---------------------------------------------------------------------------
__global__ __launch_bounds__(256)
void proj_mfma(const __bf16* __restrict__ Wb, int mstride,
               const __bf16* __restrict__ Bt,
               const float* __restrict__ bias_r, const float* __restrict__ bias_d,
               __bf16* __restrict__ dstT, __bf16* __restrict__ dstV,
               float* __restrict__ dstU,
               const float* __restrict__ resid_r, const float* __restrict__ resid_d,
               int mode, float oscale)
{
    __shared__ __bf16 As[128 * 32];
    __shared__ __bf16 Bs[128 * 32];

    const int t = threadIdx.x;
    const int n0 = blockIdx.x * 128;
    const int m0 = blockIdx.y * 128;
    const int mb = blockIdx.z;
    const int mod = mb >> 1, b = mb & 1;

    const __bf16* Am = Wb + (long)mod * mstride;
    const __bf16* Bm = Bt + (long)mb * (NPIX * 256);
    const float* bias = mod ? bias_d : bias_r;

    const int rowa = t >> 2, c16 = t & 3;
    char* ldsA0 = (char*)As + (t >> 6) * 1024;
    char* ldsA1 = ldsA0 + 4096;
    char* ldsB0 = (char*)Bs + (t >> 6) * 1024;
    char* ldsB1 = ldsB0 + 4096;
    const __bf16* srcA = Am + (long)(m0 + rowa) * 256 + c16 * 8;
    const __bf16* srcB = Bm + (long)(n0 + rowa) * 256 + c16 * 8;

    const int lane = t & 63, quad = lane >> 4, l15 = lane & 15, w = t >> 6;
    const int mw = (w >> 1) * 64, nw = (w & 1) * 64;
    const char* abase = (const char*)As + (mw + l15) * 64 + quad * 16;
    const char* bbase = (const char*)Bs + (nw + l15) * 64 + quad * 16;

    f32x4 acc[4][4];
#pragma unroll
    for (int i = 0; i < 4; ++i)
#pragma unroll
        for (int j = 0; j < 4; ++j) acc[i][j] = (f32x4)0.f;

    for (int kc = 0; kc < 256; kc += 32) {
        load_lds16(srcA + kc, ldsA0);
        load_lds16(srcA + kc + 16384, ldsA1);
        load_lds16(srcB + kc, ldsB0);
        load_lds16(srcB + kc + 16384, ldsB1);
        __syncthreads();

        bf16x8 af[4], bfr[4];
#pragma unroll
        for (int i = 0; i < 4; ++i) af[i]  = *(const bf16x8*)(abase + i * 1024);
#pragma unroll
        for (int j = 0; j < 4; ++j) bfr[j] = *(const bf16x8*)(bbase + j * 1024);
#pragma unroll
        for (int i = 0; i < 4; ++i)
#pragma unroll
            for (int j = 0; j < 4; ++j)
                acc[i][j] = __builtin_amdgcn_mfma_f32_16x16x32_bf16(
                    af[i], bfr[j], acc[i][j], 0, 0, 0);
        __syncthreads();
    }

    if (mode == 0) {
        if (mw == 0) {
            __bf16* dbase = dstT + (long)mb * (NPIX * 32);
#pragma unroll
            for (int fi = 0; fi < 2; ++fi)
#pragma unroll
                for (int r = 0; r < 4; ++r) {
                    int oc = 16 * fi + quad * 4 + r;
                    float bi = bias[oc];
#pragma unroll
                    for (int fj = 0; fj < 4; ++fj) {
                        int n = n0 + nw + 16 * fj + l15;
                        dbase[(long)n * 32 + oc] = f2b((acc[fi][fj][r] + bi) * oscale);
                    }
                }
        }
    } else if (mode == 1) {
        __bf16* dv = dstV + (long)mb * (256 * NPIX);
#pragma unroll
        for (int fi = 0; fi < 4; ++fi)
#pragma unroll
            for (int r = 0; r < 4; ++r) {
                int c = m0 + mw + 16 * fi + quad * 4 + r;
                float bi = bias[c];
                __bf16* row = dv + (long)c * NPIX;
#pragma unroll
                for (int fj = 0; fj < 4; ++fj) {
                    int n = n0 + nw + 16 * fj + l15;
                    row[n] = f2b(acc[fi][fj][r] + bi);
                }
            }
    } else {
        float* du = dstU + (long)mod * 4194304 + (long)b * 2097152;
        const float* rs = (mod ? resid_d : resid_r) + (long)b * 2097152;
#pragma unroll
        for (int fi = 0; fi < 4; ++fi)
#pragma unroll
            for (int r = 0; r < 4; ++r) {
                int oc = m0 + mw + 16 * fi + quad * 4 + r;
                float bi = bias[oc];
                const float* rrow = rs + (long)oc * NPIX;
                float* orow = du + (long)oc * NPIX;
#pragma unroll
                for (int fj = 0; fj < 4; ++fj) {
                    int n = n0 + nw + 16 * fj + l15;
                    orow[n] = acc[fi][fj][r] + bi + rrow[n];
                }
            }
    }
}

// ---------------------------------------------------------------------------
// Online MFMA row stats over a j-SEGMENT [seg*1024, +1024): partial (m, l)
// in log2 domain, single pass. grid (32 i, 4 mbo, 4 seg) = 512 blocks.
// K/Q LDS slot-swizzled ^((row>>1)&3) (conflict-free reads).
// ---------------------------------------------------------------------------
__global__ __launch_bounds__(256)
void attn_stats_mfma(const __bf16* __restrict__ Qt, const __bf16* __restrict__ Kt,
                     float* __restrict__ rmp, float* __restrict__ rlp)
{
    __shared__ __bf16 Qs[128 * 32];
    __shared__ __bf16 Ks[128 * 32];
    __shared__ float redm[2][128];
    __shared__ float redl[2][128];

    const int t  = threadIdx.x;
    const int i0 = blockIdx.x * 128;
    const int mbo = blockIdx.y;
    const int o  = mbo >> 1, b = mbo & 1;
    const int seg = blockIdx.z;
    const int jbase = seg * 1024;
    const int mbK = o * 2 + b, mbQ = (1 - o) * 2 + b;

    const __bf16* Qg = Qt + (long)mbQ * 131072;
    const __bf16* Kg = Kt + (long)mbK * 131072;

    const int lane = t & 63, quad = lane >> 4, l15 = lane & 15, w = t >> 6;
    const int mS = (w >> 1) * 64;
    const int nS = (w & 1) * 64;

    const int drow = w * 16 + (lane >> 2);                  // staging dest row
    const int ssl  = ((lane & 3) ^ ((lane >> 3) & 3)) * 16; // swizzled src slot
    const int rsl  = (quad ^ ((l15 >> 1) & 3)) << 4;        // swizzled read slot

    load_lds16((const char*)Qg + (long)(i0 + drow) * 64 + ssl, (char*)Qs + w * 1024);
    load_lds16((const char*)Qg + (long)(i0 + 64 + drow) * 64 + ssl,
               (char*)Qs + 4096 + w * 1024);
    __syncthreads();

    bf16x8 qa[4];
#pragma unroll
    for (int fi = 0; fi < 4; ++fi)
        qa[fi] = *(const bf16x8*)((const char*)Qs + (mS + 16 * fi + l15) * 64 + rsl);

    const f32x4 zero4 = (f32x4)0.f;
    float m_t[16], l_t[16];
#pragma unroll
    for (int e = 0; e < 16; ++e) { m_t[e] = -3.0e38f; l_t[e] = 0.f; }

    for (int j0 = jbase; j0 < jbase + 1024; j0 += 128) {
        __syncthreads();
        load_lds16((const char*)Kg + (long)(j0 + drow) * 64 + ssl, (char*)Ks + w * 1024);
        load_lds16((const char*)Kg + (long)(j0 + 64 + drow) * 64 + ssl,
                   (char*)Ks + 4096 + w * 1024);
        __syncthreads();

        bf16x8 kb[4];
#pragma unroll
        for (int fj = 0; fj < 4; ++fj)
            kb[fj] = *(const bf16x8*)((const char*)Ks + (nS + 16 * fj + l15) * 64 + rsl);
#pragma unroll
        for (int fi = 0; fi < 4; ++fi) {
            f32x4 sf[4];
#pragma unroll
            for (int fj = 0; fj < 4; ++fj)
                sf[fj] = __builtin_amdgcn_mfma_f32_16x16x32_bf16(qa[fi], kb[fj], zero4, 0, 0, 0);
#pragma unroll
            for (int r = 0; r < 4; ++r) {
                int e = fi * 4 + r;
                float a = fmaxf(fmaxf(sf[0][r], sf[1][r]), fmaxf(sf[2][r], sf[3][r]));
                float nm = fmaxf(m_t[e], a);
                float s = exp2f(sf[0][r] - nm) + exp2f(sf[1][r] - nm)
                        + exp2f(sf[2][r] - nm) + exp2f(sf[3][r] - nm);
                l_t[e] = l_t[e] * exp2f(m_t[e] - nm) + s;
                m_t[e] = nm;
            }
        }
    }

#pragma unroll
    for (int d = 1; d < 16; d <<= 1)
#pragma unroll
        for (int e = 0; e < 16; ++e) {
            float om = __shfl_xor(m_t[e], d, 64);
            float ol = __shfl_xor(l_t[e], d, 64);
            float nm = fmaxf(m_t[e], om);
            l_t[e] = l_t[e] * exp2f(m_t[e] - nm) + ol * exp2f(om - nm);
            m_t[e] = nm;
        }
    if (l15 == 0) {
#pragma unroll
        for (int fi = 0; fi < 4; ++fi)
#pragma unroll
            for (int r = 0; r < 4; ++r) {
                redm[w & 1][mS + 16 * fi + quad * 4 + r] = m_t[fi * 4 + r];
                redl[w & 1][mS + 16 * fi + quad * 4 + r] = l_t[fi * 4 + r];
            }
    }
    __syncthreads();
    if (t < 128) {
        float m0 = redm[0][t], m1 = redm[1][t];
        float l0 = redl[0][t], l1 = redl[1][t];
        float m = fmaxf(m0, m1);
        float l = l0 * exp2f(m0 - m) + l1 * exp2f(m1 - m);
        rmp[seg * 16384 + mbo * 4096 + i0 + t] = m;
        rlp[seg * 16384 + mbo * 4096 + i0 + t] = l;
    }
}

// ---------------------------------------------------------------------------
// Merge 4-segment stats: m = max, rl = 1/sum(l_s * 2^(m_s-m)). grid 64x256.
// ---------------------------------------------------------------------------
__global__ __launch_bounds__(256)
void stats_merge(const float* __restrict__ rmp, const float* __restrict__ rlp,
                 float* __restrict__ rmb, float* __restrict__ rlb)
{
    int idx = blockIdx.x * 256 + threadIdx.x;
    float m = rmp[idx];
#pragma unroll
    for (int s = 1; s < 4; ++s) m = fmaxf(m, rmp[s * 16384 + idx]);
    float l = 0.f;
#pragma unroll
    for (int s = 0; s < 4; ++s)
        l += rlp[s * 16384 + idx] * exp2f(rmp[s * 16384 + idx] - m);
    rmb[idx] = m;
    rlb[idx] = 1.f / l;
}

// ---------------------------------------------------------------------------
// Fused MFMA PV v4: round-3 structure (i64, c256, j-step 64, 48KB LDS,
// 2 blocks/CU) + round-11 fixes (conflict-free swizzles, XCD grouping).
// Linear grid 512; bx&7 = (mb<<1)|seg -> the 64 i-blocks sharing one 1MB
// V-slice live on one XCD (V/K L2-resident). Wave w: S rows [16w,16w+16),
// PV c rows [64w,64w+64), acc 4x4.
// Swizzles: Q/K/V phys slot = logical ^ ((row>>1)&3) (inverse on global src,
// linear global_load_lds dest); P byte ^= (il&7)<<4 (rows 128B).
// ---------------------------------------------------------------------------
__global__ __launch_bounds__(256, 2)
void attn_pv_mfma(const __bf16* __restrict__ Qt, const __bf16* __restrict__ Kt,
                  const __bf16* __restrict__ Vb,
                  float* __restrict__ part0, float* __restrict__ part1,
                  const float* __restrict__ rmb, const float* __restrict__ rlb)
{
    __shared__ __bf16 Qs[64 * 32];        // 4KB  [64 i][32ch]
    __shared__ __bf16 Ks[64 * 32];        // 4KB  [64 j][32ch]
    __shared__ __bf16 Vs[2 * 256 * 32];   // 32KB [2ks][256c][32j]
    __shared__ __bf16 Ps[64 * 64];        // 8KB  [64 i][64 j] swizzled

    const int t  = threadIdx.x;
    const int bx = blockIdx.x;
    const int grp = bx & 7;               // XCD group = (mb<<1)|seg
    const int i0  = (bx >> 3) * 64;
    const int seg = grp & 1;
    const int mb  = grp >> 1;
    const int o  = mb >> 1, b = mb & 1;
    const int mbQ = (1 - o) * 2 + b;
    const int jbase = seg * 2048;

    const __bf16* Qg = Qt + (long)mbQ * 131072;
    const __bf16* Kg = Kt + (long)mb * 131072;
    const __bf16* Vg = Vb + (long)mb * 1048576;
    const float* rm = rmb + mb * 4096;
    const float* rl = rlb + mb * 4096;

    const int lane = t & 63, quad = lane >> 4, l15 = lane & 15, w = t >> 6;
    const int iS = w * 16;                // this wave's S row block
    const int cw = w * 64;                // this wave's PV c block

    const int drow = w * 16 + (lane >> 2);                  // staging dest row
    const int ssl  = ((lane & 3) ^ ((lane >> 3) & 3)) * 16; // swizzled src slot
    const int rsl  = (quad ^ ((l15 >> 1) & 3)) << 4;        // swizzled read slot

    // Q stage (64 rows, 4KB)
    load_lds16((const char*)Qg + (long)(i0 + drow) * 64 + ssl, (char*)Qs + w * 1024);

    float mlv[4], rlv[4];
#pragma unroll
    for (int r = 0; r < 4; ++r) mlv[r] = rm[i0 + iS + quad * 4 + r];
#pragma unroll
    for (int fj = 0; fj < 4; ++fj) rlv[fj] = rl[i0 + 16 * fj + l15];

    f32x4 acc[4][4];
#pragma unroll
    for (int i = 0; i < 4; ++i)
#pragma unroll
        for (int j = 0; j < 4; ++j) acc[i][j] = (f32x4)0.f;
    const f32x4 zero4 = (f32x4)0.f;

    __syncthreads();
    const bf16x8 qa = *(const bf16x8*)((const char*)Qs + (iS + l15) * 64 + rsl);

    for (int j0 = jbase; j0 < jbase + 2048; j0 += 64) {
        __syncthreads();                    // prev-step consumers done
        load_lds16((const char*)Kg + (long)(j0 + drow) * 64 + ssl,
                   (char*)Ks + w * 1024);
        __syncthreads();                    // K ready (only K in flight)

        // issue V loads now; latency hides under S + P (drained at next barrier)
#pragma unroll
        for (int ii = 0; ii < 8; ++ii) {
            int ks = ii >> 2;
            int c  = (ii & 3) * 64 + drow;
            load_lds16((const char*)Vg + (long)c * 8192 + (long)(j0 + ks * 32) * 2 + ssl,
                       (char*)Vs + ii * 4096 + w * 1024);
        }

        // S = Q K^T for rows [iS,iS+16), cols [0,64)
        f32x4 sA[4];
#pragma unroll
        for (int fj = 0; fj < 4; ++fj) {
            bf16x8 kb = *(const bf16x8*)((const char*)Ks + (16 * fj + l15) * 64 + rsl);
            sA[fj] = __builtin_amdgcn_mfma_f32_16x16x32_bf16(qa, kb, zero4, 0, 0, 0);
        }
        // P = exp2(S - m) -> swizzled Ps
#pragma unroll
        for (int fj = 0; fj < 4; ++fj)
#pragma unroll
            for (int r = 0; r < 4; ++r) {
                int il = iS + quad * 4 + r;
                int boff = (il * 128 + (16 * fj + l15) * 2) ^ ((il & 7) << 4);
                *(__bf16*)((char*)Ps + boff) = f2b(exp2f(sA[fj][r] - mlv[r]));
            }
        __syncthreads();                    // P visible, V staged

#pragma unroll
        for (int ks = 0; ks < 2; ++ks) {
            bf16x8 va[4], pb[4];
#pragma unroll
            for (int fi = 0; fi < 4; ++fi)
                va[fi] = *(const bf16x8*)((const char*)Vs + ks * 16384 +
                                          (cw + 16 * fi + l15) * 64 + rsl);
#pragma unroll
            for (int fj = 0; fj < 4; ++fj) {
                int ip = 16 * fj + l15;
                int boff = (ip * 128 + ks * 64 + quad * 16) ^ ((ip & 7) << 4);
                pb[fj] = *(const bf16x8*)((const char*)Ps + boff);
            }
#pragma unroll
            for (int fi = 0; fi < 4; ++fi)
#pragma unroll
                for (int fj = 0; fj < 4; ++fj)
                    acc[fi][fj] = __builtin_amdgcn_mfma_f32_16x16x32_bf16(
                        va[fi], pb[fj], acc[fi][fj], 0, 0, 0);
        }
    }

    // partial store, rl folded here (acc * 1/l)
    float* pg = (seg ? part1 : part0) + (long)mb * 1048576;
#pragma unroll
    for (int fi = 0; fi < 4; ++fi) {
#pragma unroll
        for (int r = 0; r < 4; ++r) {
            int c = cw + 16 * fi + quad * 4 + r;
            float* zr = pg + (long)c * 4096;
#pragma unroll
            for (int fj = 0; fj < 4; ++fj)
                zr[i0 + 16 * fj + l15] = acc[fi][fj][r] * rlv[fj];
        }
    }
}

// ---------------------------------------------------------------------------
// z = gamma*(part0+part1) + conv, transposed bf16 store to Zt[pix][256].
// grid (128, 8, 4).
// ---------------------------------------------------------------------------
__global__ __launch_bounds__(256)
void zred_t(const float* __restrict__ p0, const float* __restrict__ p1,
            const float* __restrict__ convb, __bf16* __restrict__ Zt,
            const float* __restrict__ g_r, const float* __restrict__ g_d)
{
    __shared__ float tile[32][33];
    const int t = threadIdx.x;
    const int pix0 = blockIdx.x * 32;
    const int c0 = blockIdx.y * 32;
    const int mb = blockIdx.z;
    const int o = mb >> 1;
    const float gamma = (o ? g_d : g_r)[0];
    const long base = (long)mb * 1048576;

    int i = t >> 3, j4 = (t & 7) * 4;
    long row = base + (long)(c0 + i) * 4096 + pix0 + j4;
    float4 a = *(const float4*)&p0[row];
    float4 b = *(const float4*)&p1[row];
    float4 cv = *(const float4*)&convb[row];
    tile[i][j4 + 0] = gamma * (a.x + b.x) + cv.x;
    tile[i][j4 + 1] = gamma * (a.y + b.y) + cv.y;
    tile[i][j4 + 2] = gamma * (a.z + b.z) + cv.z;
    tile[i][j4 + 3] = gamma * (a.w + b.w) + cv.w;
    __syncthreads();
    int j = t >> 3, i4 = (t & 7) * 4;
    bf16x4 oq;
    oq.x = f2b(tile[i4 + 0][j]); oq.y = f2b(tile[i4 + 1][j]);
    oq.z = f2b(tile[i4 + 2][j]); oq.w = f2b(tile[i4 + 3][j]);
    *(bf16x4*)&Zt[(long)mb * NPIX * 256 + (long)(pix0 + j) * 256 + c0 + i4] = oq;
}

// ---------------------------------------------------------------------------
// Host launcher (ws layout unchanged — see round 10 comment)
// ---------------------------------------------------------------------------
extern "C" void kernel_launch(void* const* d_in, const int* in_sizes, int n_in,
                              void* d_out, int out_size, void* d_ws, size_t ws_size,
                              hipStream_t stream)
{
    const float* in_rgb = (const float*)d_in[0];
    const float* in_dsm = (const float*)d_in[1];
    auto P = [&](int i) { return (const float*)d_in[i]; };

    float* ws    = (float*)d_ws;
    float* conv  = ws;
    float* part0 = ws + 4194304;
    float* rmb   = ws + 8388608;
    float* rlb   = ws + 8404992;
    float* rmp   = part0;            // [4][4][4096] scratch, dead before pv
    float* rlp   = part0 + 65536;
    float* scA   = ws + 8486912;
    float* shB   = ws + 8487424;
    __bf16* zrow = (__bf16*)(ws + 8487936);
    __bf16* Wt   = (__bf16*)(ws + 8488192);
    __bf16* Xp   = (__bf16*)(ws + 9667840);
    float*  part1 = ws + 9667840;            // aliases Xp (dead after conv)
    __bf16* Qt   = (__bf16*)(ws + 13862144);
    __bf16* Kt   = (__bf16*)(ws + 14124288);
    __bf16* Vbb  = (__bf16*)(ws + 14386432);
    __bf16* Ct   = (__bf16*)(ws + 16483584);
    __bf16* Zt   = (__bf16*)(ws + 18580736);
    __bf16* Wq   = (__bf16*)(ws + 20677888);
    __bf16* Wk   = (__bf16*)(ws + 20710656);
    __bf16* Wv   = (__bf16*)(ws + 20743424);
    __bf16* Wu   = (__bf16*)(ws + 20808960);

    // prep
    prep_w<<<2307, 256, 0, stream>>>(
        P(2), P(18), P(3), P(4), P(5), P(6), P(7),
        P(19), P(20), P(21), P(22), P(23),
        Wt, scA, shB, zrow);
    prep_gw<<<512, 256, 0, stream>>>(
        P(9), P(25), P(11), P(27), P(13), P(29), P(15), P(31),
        Wq, Wk, Wv, Wu);
    xpose<<<dim3(128, 16, 4), 256, 0, stream>>>(in_rgb, in_dsm, Xp);

    // conv3x3 + BN + PReLU (v3: halo, 256 blocks = 1/CU, counted vmcnt)
    conv_mfma<<<dim3(16, 4, 4), 256, 0, stream>>>(
        Wt, Xp, zrow, scA, shB, P(8), P(24), conv);
    t256<<<dim3(128, 8, 4), 256, 0, stream>>>(conv, Ct);

    // q/k/v projections (Q pre-scaled by log2e -> exp2 softmax domain)
    proj_mfma<<<dim3(32, 1, 4), 256, 0, stream>>>(
        Wq, 32768, Ct, P(10), P(26), Qt, nullptr, nullptr, nullptr, nullptr,
        0, 1.4426950408889634f);
    proj_mfma<<<dim3(32, 1, 4), 256, 0, stream>>>(
        Wk, 32768, Ct, P(12), P(28), Kt, nullptr, nullptr, nullptr, nullptr,
        0, 1.0f);
    proj_mfma<<<dim3(32, 2, 4), 256, 0, stream>>>(
        Wv, 65536, Ct, P(14), P(30), nullptr, Vbb, nullptr, nullptr, nullptr,
        1, 1.0f);

    // online softmax stats (j-split x4, 512 blocks) + merge
    attn_stats_mfma<<<dim3(32, 4, 4), 256, 0, stream>>>(Qt, Kt, rmp, rlp);
    stats_merge<<<64, 256, 0, stream>>>(rmp, rlp, rmb, rlb);

    // fused PV v4 (linear grid 512, XCD-grouped, 2 blocks/CU)
    attn_pv_mfma<<<512, 256, 0, stream>>>(
        Qt, Kt, Vbb, part0, part1, rmb, rlb);

    // z = gamma*(p0+p1)+conv, transpose + bf16 -> Zt
    zred_t<<<dim3(128, 8, 4), 256, 0, stream>>>(
        part0, part1, conv, Zt, P(17), P(33));

    // up projection + input residual -> fp32 out
    proj_mfma<<<dim3(32, 4, 4), 256, 0, stream>>>(
        Wu, 131072, Zt, P(16), P(32), nullptr, nullptr, (float*)d_out,
        in_rgb, in_dsm, 2, 1.0f);
}

// Round 6
// 356.970 us; speedup vs baseline: 1.0476x; 1.0183x over previous
//
#include <hip/hip_runtime.h>
#include <hip/hip_bf16.h>
#include <stdint.h>

// fp32 I/O. Conv3x3, 1x1 projections, and attention run as bf16 MFMA.
// Softmax stats (m,l) and P come from the SAME bf16 MFMA S path (unscaled
// attention -> near-argmax softmax; any S mismatch scales o by exp(dS)).
// Round 11: pv i128 1-block/CU: conflict+L3 fixes verified, but 1 wave/SIMD
//   exposed latency (79us). Round 12: pv v4 = 2 blocks/CU + fixes -> off top-5.
// Round 13 (this): conv v4 — SAME halo structure/traffic/K-order, but the
//   block re-partitioned over 8 waves (512 threads): wave = oc-half x y-row,
//   tile 32oc x 64pix, acc 2x4. 2 waves/SIMD hides ds_read->MFMA latency
//   (conv was 1 wave/SIMD, Occupancy 10%, MfmaUtil 22%). LDS/step 64->96KB
//   (floor 22.5us) — still far under the 67.5us measured. vmcnt re-derived:
//   stage_a=1 load/thread, stage_b=6 -> steady vmcnt(1), B-in-flight vmcnt(7).

constexpr int CINCH = 512;
constexpr int NPIX  = 4096;   // 64*64

typedef __bf16 bf16x8 __attribute__((ext_vector_type(8)));
typedef __bf16 bf16x4 __attribute__((ext_vector_type(4)));
typedef float  f32x4  __attribute__((ext_vector_type(4)));

__device__ __forceinline__ __bf16 f2b(float f) {
    __hip_bfloat16 h = __float2bfloat16(f);
    return *reinterpret_cast<__bf16*>(&h);
}

__device__ __forceinline__ void load_lds16(const void* g, void* l) {
    __builtin_amdgcn_global_load_lds(
        (const __attribute__((address_space(1))) unsigned int*)(uintptr_t)g,
        (__attribute__((address_space(3))) unsigned int*)(uintptr_t)l,
        16, 0, 0);
}

// ---------------------------------------------------------------------------
// Prep A: conv weights fp32 [oc][ic][9] -> Wt bf16 [mod][tap][oc][ic];
// BN scale/shift tables; zero row. grid 2307 x 256.
// ---------------------------------------------------------------------------
__global__ __launch_bounds__(256)
void prep_w(const float* __restrict__ w_r, const float* __restrict__ w_d,
            const float* __restrict__ cb_r, const float* __restrict__ bg_r,
            const float* __restrict__ bb_r, const float* __restrict__ bm_r,
            const float* __restrict__ bv_r,
            const float* __restrict__ cb_d, const float* __restrict__ bg_d,
            const float* __restrict__ bb_d, const float* __restrict__ bm_d,
            const float* __restrict__ bv_d,
            __bf16* __restrict__ Wt, float* __restrict__ scA,
            float* __restrict__ shB, __bf16* __restrict__ zrow)
{
    const int t = threadIdx.x;
    const int blk = blockIdx.x;
    if (blk < 2304) {
        int gid = blk * 1024 + t * 4;
        int mod = gid >= 1179648;
        int o2  = gid - mod * 1179648;
        int tap = o2 >> 17;
        int r   = o2 & 131071;
        int oc  = r >> 9;
        int ic  = r & 511;
        const float* wsrc = mod ? w_d : w_r;
        long base = ((long)(oc * 512 + ic)) * 9 + tap;
        bf16x4 v;
        v.x = f2b(wsrc[base]);
        v.y = f2b(wsrc[base + 9]);
        v.z = f2b(wsrc[base + 18]);
        v.w = f2b(wsrc[base + 27]);
        *(bf16x4*)&Wt[gid] = v;
    } else if (blk == 2304) {
        unsigned short* z = (unsigned short*)zrow;
        z[t] = 0; z[t + 256] = 0;
    } else {
        int mod = blk - 2305;
        const float* cb = mod ? cb_d : cb_r;
        const float* bg = mod ? bg_d : bg_r;
        const float* bb = mod ? bb_d : bb_r;
        const float* bm = mod ? bm_d : bm_r;
        const float* bv = mod ? bv_d : bv_r;
        int oc = t;
        float sc = bg[oc] * rsqrtf(bv[oc] + 1e-5f);
        scA[mod * 256 + oc] = sc;
        shB[mod * 256 + oc] = (cb[oc] - bm[oc]) * sc + bb[oc];
    }
}

// ---------------------------------------------------------------------------
// Prep B: projection weights fp32 -> bf16. Wq/Wk padded to 128 rows (zeros).
// ---------------------------------------------------------------------------
__global__ __launch_bounds__(256)
void prep_gw(const float* __restrict__ qw_r, const float* __restrict__ qw_d,
             const float* __restrict__ kw_r, const float* __restrict__ kw_d,
             const float* __restrict__ vw_r, const float* __restrict__ vw_d,
             const float* __restrict__ uw_r, const float* __restrict__ uw_d,
             __bf16* __restrict__ Wq, __bf16* __restrict__ Wk,
             __bf16* __restrict__ Wv, __bf16* __restrict__ Wu)
{
    int gid = blockIdx.x * 1024 + threadIdx.x * 4;
    __bf16* dst;
    float4 f = make_float4(0.f, 0.f, 0.f, 0.f);
    if (gid < 65536) {
        int mod = gid >> 15, e = gid & 32767;
        dst = Wq + gid;
        if (e < 8192) f = *(const float4*)((mod ? qw_d : qw_r) + e);
    } else if (gid < 131072) {
        int g = gid - 65536;
        int mod = g >> 15, e = g & 32767;
        dst = Wk + g;
        if (e < 8192) f = *(const float4*)((mod ? kw_d : kw_r) + e);
    } else if (gid < 262144) {
        int g = gid - 131072;
        int mod = g >> 16, e = g & 65535;
        dst = Wv + g;
        f = *(const float4*)((mod ? vw_d : vw_r) + e);
    } else {
        int g = gid - 262144;
        int mod = g >> 17, e = g & 131071;
        dst = Wu + g;
        f = *(const float4*)((mod ? uw_d : uw_r) + e);
    }
    bf16x4 o; o.x = f2b(f.x); o.y = f2b(f.y); o.z = f2b(f.z); o.w = f2b(f.w);
    *(bf16x4*)dst = o;
}

// ---------------------------------------------------------------------------
// Prep C: X fp32 [mod][b][512][4096] -> Xp bf16 [modb][4096pix][512ic]
// ---------------------------------------------------------------------------
__global__ __launch_bounds__(256)
void xpose(const float* __restrict__ inr, const float* __restrict__ ind,
           __bf16* __restrict__ Xp)
{
    __shared__ float tile[32][33];
    const int t = threadIdx.x;
    const int p0 = blockIdx.x * 32;
    const int ic0 = blockIdx.y * 32;
    const int mb = blockIdx.z;
    const int mod = mb >> 1, b = mb & 1;
    const float* src = (mod ? ind : inr) + (long)b * CINCH * NPIX;

    int i = t >> 3, j4 = (t & 7) * 4;
    float4 v = *(const float4*)&src[(long)(ic0 + i) * NPIX + p0 + j4];
    tile[i][j4 + 0] = v.x; tile[i][j4 + 1] = v.y;
    tile[i][j4 + 2] = v.z; tile[i][j4 + 3] = v.w;
    __syncthreads();
    int j = t >> 3, i4 = (t & 7) * 4;
    bf16x4 o;
    o.x = f2b(tile[i4 + 0][j]);
    o.y = f2b(tile[i4 + 1][j]);
    o.z = f2b(tile[i4 + 2][j]);
    o.w = f2b(tile[i4 + 3][j]);
    *(bf16x4*)&Xp[((long)mb * NPIX + p0 + j) * 512 + ic0 + i4] = o;
}

// ---------------------------------------------------------------------------
// fp32 [mb][256][4096] -> bf16 transposed [mb][4096][256]. grid (128, 8, 4).
// ---------------------------------------------------------------------------
__global__ __launch_bounds__(256)
void t256(const float* __restrict__ src, __bf16* __restrict__ dst)
{
    __shared__ float tile[32][33];
    const int t = threadIdx.x;
    const int p0 = blockIdx.x * 32;
    const int c0 = blockIdx.y * 32;
    const int mb = blockIdx.z;
    const float* s = src + (long)mb * 256 * NPIX;
    __bf16* d = dst + (long)mb * NPIX * 256;

    int i = t >> 3, j4 = (t & 7) * 4;
    float4 v = *(const float4*)&s[(long)(c0 + i) * NPIX + p0 + j4];
    tile[i][j4 + 0] = v.x; tile[i][j4 + 1] = v.y;
    tile[i][j4 + 2] = v.z; tile[i][j4 + 3] = v.w;
    __syncthreads();
    int j = t >> 3, i4 = (t & 7) * 4;
    bf16x4 o;
    o.x = f2b(tile[i4 + 0][j]); o.y = f2b(tile[i4 + 1][j]);
    o.z = f2b(tile[i4 + 2][j]); o.w = f2b(tile[i4 + 3][j]);
    *(bf16x4*)&d[((long)(p0 + j)) * 256 + c0 + i4] = o;
}

// ---------------------------------------------------------------------------
// Conv3x3 implicit-GEMM MFMA v4 (halo, 8 waves).
// Block: 64oc x 256pix (4 y-rows), 512 threads (8 waves).
// Wave w: oc-half wo=w>>2 (32 oc), y-row wy=w&3, acc 2x4.
// Same halo staging / K-order / swizzle / counted-vmcnt as v3; per-thread
// load counts: stage_a=1, stage_b=6. 2 waves/SIMD hides LDS latency.
// grid (16 pixtiles, 4 octiles, 4 mb) = 256 blocks, 120.25KB LDS.
// ---------------------------------------------------------------------------
__global__ __launch_bounds__(512)
void conv_mfma(const __bf16* __restrict__ Wt, const __bf16* __restrict__ Xp,
               const __bf16* __restrict__ zrow, const float* __restrict__ scA,
               const float* __restrict__ shB, const float* __restrict__ prr,
               const float* __restrict__ prd, float* __restrict__ conv)
{
    __shared__ __bf16 As[3 * 64 * 64];      // 24 KB
    __shared__ __bf16 Bs[2 * 385 * 64];     // 96.25 KB (row 384 = zeros)

    const int t = threadIdx.x;
    const int y0 = blockIdx.x * 4;
    const int m0 = blockIdx.y * 64;
    const int mb = blockIdx.z;
    const int mod = mb >> 1;

    const __bf16* Am = Wt + (long)mod * (9 * 256 * 512);
    const __bf16* Xb = Xp + (long)mb * NPIX * 512;

    const int lane = t & 63, quad = lane >> 4, l15 = lane & 15, w = t >> 6;
    const int wy = w & 3, wo = w >> 2;

    // zero rows (row 384 of each B buffer)
    if (t < 16)
        *(f32x4*)((char*)Bs + (t >> 3) * 49280 + 49152 + (t & 7) * 16) = (f32x4)0.f;
    asm volatile("s_waitcnt lgkmcnt(0)" ::: "memory");

    // ---- staging (linear LDS dest = uniform base + lane*16; swizzled src) ----
    auto stage_a = [&](int buf, int tap, int cc) {   // 1 load/thread (8KB)
        int r  = w * 8 + (lane >> 3);
        int sl = (lane & 7) ^ (r & 7);
        const __bf16* src = Am + (long)tap * 131072 + (long)(m0 + r) * 512
                          + cc * 64 + sl * 8;
        load_lds16(src, (char*)As + buf * 8192 + w * 1024);
    };
    auto stage_b = [&](int buf, int cc) {            // 6 loads/thread (48KB)
#pragma unroll
        for (int k = 0; k < 6; ++k) {
            int r  = w * 48 + k * 8 + (lane >> 3);
            int sl = (lane & 7) ^ (r & 7);
            int hr = r >> 6, xx = r & 63;
            int gy = y0 + hr - 1;
            const __bf16* src = ((unsigned)gy < 64u)
                ? Xb + (long)(gy * 64 + xx) * 512 + cc * 64 + sl * 8
                : zrow + sl * 8;
            load_lds16(src, (char*)Bs + buf * 49280 + (w * 48 + k * 8) * 128);
        }
    };

    f32x4 acc[2][4];
#pragma unroll
    for (int i = 0; i < 2; ++i)
#pragma unroll
        for (int j = 0; j < 4; ++j) acc[i][j] = (f32x4)0.f;

    stage_b(0, 0);
    stage_a(0, 0, 0);
    stage_a(1, 1, 0);

    const int soffA0 = ((quad ^ (l15 & 7)) << 4);
    const int soffA1 = (((4 | quad) ^ (l15 & 7)) << 4);

    for (int c = 0; c < 8; ++c) {
        for (int tp = 0; tp < 9; ++tp) {
            const int s = c * 9 + tp;
            // counted wait: A(s) [and B(c) at tp==0] done, newer stay in flight
            if (s == 71)                  { asm volatile("s_waitcnt vmcnt(0)" ::: "memory"); }
            else if (tp >= 7 && c < 7)    { asm volatile("s_waitcnt vmcnt(7)" ::: "memory"); }
            else                          { asm volatile("s_waitcnt vmcnt(1)" ::: "memory"); }
            __builtin_amdgcn_sched_barrier(0);
            __builtin_amdgcn_s_barrier();
            __builtin_amdgcn_sched_barrier(0);

            if (s + 2 < 72) {
                int c2 = (tp + 2 >= 9) ? c + 1 : c;
                int t2 = (tp + 2 >= 9) ? tp - 7 : tp + 2;
                int b2 = (s + 2) % 3;
                stage_a(b2, t2, c2);
            }
            __builtin_amdgcn_sched_barrier(0);
            if (tp == 6 && c < 7) stage_b((c + 1) & 1, c + 1);
            __builtin_amdgcn_sched_barrier(0);

            // compute tap tp on chunk c: wave = 32oc (wo) x 64pix (row wy)
            const char* ab = (const char*)As + (s % 3) * 8192;
            const char* bb = (const char*)Bs + (c & 1) * 49280;
            const int dy = tp / 3 - 1, dx = tp % 3 - 1;
            const int hr = wy + 1 + dy;
            int rb[4];
#pragma unroll
            for (int fj = 0; fj < 4; ++fj) {
                int x = fj * 16 + l15 + dx;
                rb[fj] = ((unsigned)x < 64u) ? hr * 64 + x : 384;
            }
#pragma unroll
            for (int kk = 0; kk < 2; ++kk) {
                const int slq = kk * 4 + quad;
                bf16x8 af[2], bfr[4];
#pragma unroll
                for (int i = 0; i < 2; ++i)
                    af[i] = *(const bf16x8*)(ab + (wo * 32 + 16 * i + l15) * 128
                                             + (kk ? soffA1 : soffA0));
#pragma unroll
                for (int fj = 0; fj < 4; ++fj)
                    bfr[fj] = *(const bf16x8*)(bb + rb[fj] * 128
                                               + ((slq ^ (rb[fj] & 7)) << 4));
#pragma unroll
                for (int i = 0; i < 2; ++i)
#pragma unroll
                    for (int fj = 0; fj < 4; ++fj)
                        acc[i][fj] = __builtin_amdgcn_mfma_f32_16x16x32_bf16(
                            af[i], bfr[fj], acc[i][fj], 0, 0, 0);
            }
        }
    }

    // epilogue: BN + PReLU, fp32 store. wave -> oc half wo, pixel row y0+wy.
    const float alpha = (mod ? prd : prr)[0];
    float* outp = conv + (long)mb * 256 * NPIX;
    const int nbase = (y0 + wy) * 64;
#pragma unroll
    for (int i = 0; i < 2; ++i) {
#pragma unroll
        for (int r = 0; r < 4; ++r) {
            int oc = m0 + wo * 32 + 16 * i + quad * 4 + r;
            float sc = scA[mod * 256 + oc];
            float sh = shB[mod * 256 + oc];
            float* orow = outp + (long)oc * NPIX;
#pragma unroll
            for (int fj = 0; fj < 4; ++fj) {
                int n = nbase + 16 * fj + l15;
                float y = acc[i][fj][r] * sc + sh;
                y = (y > 0.f) ? y : alpha * y;
                orow[n] = y;
            }
        }
    }
}

// ---------------------------------------------------------------------------
// 1x1-projection MFMA GEMM. mode 0 output scaled by oscale (log2e for Q).
// ---------------------------------------------------------------------------
__global__ __launch_bounds__(256)
void proj_mfma(const __bf16* __restrict__ Wb, int mstride,
               const __bf16* __restrict__ Bt,
               const float* __restrict__ bias_r, const float* __restrict__ bias_d,
               __bf16* __restrict__ dstT, __bf16* __restrict__ dstV,
               float* __restrict__ dstU,
               const float* __restrict__ resid_r, const float* __restrict__ resid_d,
               int mode, float oscale)
{
    __shared__ __bf16 As[128 * 32];
    __shared__ __bf16 Bs[128 * 32];

    const int t = threadIdx.x;
    const int n0 = blockIdx.x * 128;
    const int m0 = blockIdx.y * 128;
    const int mb = blockIdx.z;
    const int mod = mb >> 1, b = mb & 1;

    const __bf16* Am = Wb + (long)mod * mstride;
    const __bf16* Bm = Bt + (long)mb * (NPIX * 256);
    const float* bias = mod ? bias_d : bias_r;

    const int rowa = t >> 2, c16 = t & 3;
    char* ldsA0 = (char*)As + (t >> 6) * 1024;
    char* ldsA1 = ldsA0 + 4096;
    char* ldsB0 = (char*)Bs + (t >> 6) * 1024;
    char* ldsB1 = ldsB0 + 4096;
    const __bf16* srcA = Am + (long)(m0 + rowa) * 256 + c16 * 8;
    const __bf16* srcB = Bm + (long)(n0 + rowa) * 256 + c16 * 8;

    const int lane = t & 63, quad = lane >> 4, l15 = lane & 15, w = t >> 6;
    const int mw = (w >> 1) * 64, nw = (w & 1) * 64;
    const char* abase = (const char*)As + (mw + l15) * 64 + quad * 16;
    const char* bbase = (const char*)Bs + (nw + l15) * 64 + quad * 16;

    f32x4 acc[4][4];
#pragma unroll
    for (int i = 0; i < 4; ++i)
#pragma unroll
        for (int j = 0; j < 4; ++j) acc[i][j] = (f32x4)0.f;

    for (int kc = 0; kc < 256; kc += 32) {
        load_lds16(srcA + kc, ldsA0);
        load_lds16(srcA + kc + 16384, ldsA1);
        load_lds16(srcB + kc, ldsB0);
        load_lds16(srcB + kc + 16384, ldsB1);
        __syncthreads();

        bf16x8 af[4], bfr[4];
#pragma unroll
        for (int i = 0; i < 4; ++i) af[i]  = *(const bf16x8*)(abase + i * 1024);
#pragma unroll
        for (int j = 0; j < 4; ++j) bfr[j] = *(const bf16x8*)(bbase + j * 1024);
#pragma unroll
        for (int i = 0; i < 4; ++i)
#pragma unroll
            for (int j = 0; j < 4; ++j)
                acc[i][j] = __builtin_amdgcn_mfma_f32_16x16x32_bf16(
                    af[i], bfr[j], acc[i][j], 0, 0, 0);
        __syncthreads();
    }

    if (mode == 0) {
        if (mw == 0) {
            __bf16* dbase = dstT + (long)mb * (NPIX * 32);
#pragma unroll
            for (int fi = 0; fi < 2; ++fi)
#pragma unroll
                for (int r = 0; r < 4; ++r) {
                    int oc = 16 * fi + quad * 4 + r;
                    float bi = bias[oc];
#pragma unroll
                    for (int fj = 0; fj < 4; ++fj) {
                        int n = n0 + nw + 16 * fj + l15;
                        dbase[(long)n * 32 + oc] = f2b((acc[fi][fj][r] + bi) * oscale);
                    }
                }
        }
    } else if (mode == 1) {
        __bf16* dv = dstV + (long)mb * (256 * NPIX);
#pragma unroll
        for (int fi = 0; fi < 4; ++fi)
#pragma unroll
            for (int r = 0; r < 4; ++r) {
                int c = m0 + mw + 16 * fi + quad * 4 + r;
                float bi = bias[c];
                __bf16* row = dv + (long)c * NPIX;
#pragma unroll
                for (int fj = 0; fj < 4; ++fj) {
                    int n = n0 + nw + 16 * fj + l15;
                    row[n] = f2b(acc[fi][fj][r] + bi);
                }
            }
    } else {
        float* du = dstU + (long)mod * 4194304 + (long)b * 2097152;
        const float* rs = (mod ? resid_d : resid_r) + (long)b * 2097152;
#pragma unroll
        for (int fi = 0; fi < 4; ++fi)
#pragma unroll
            for (int r = 0; r < 4; ++r) {
                int oc = m0 + mw + 16 * fi + quad * 4 + r;
                float bi = bias[oc];
                const float* rrow = rs + (long)oc * NPIX;
                float* orow = du + (long)oc * NPIX;
#pragma unroll
                for (int fj = 0; fj < 4; ++fj) {
                    int n = n0 + nw + 16 * fj + l15;
                    orow[n] = acc[fi][fj][r] + bi + rrow[n];
                }
            }
    }
}

// ---------------------------------------------------------------------------
// Online MFMA row stats over a j-SEGMENT [seg*1024, +1024): partial (m, l)
// in log2 domain, single pass. grid (32 i, 4 mbo, 4 seg) = 512 blocks.
// K/Q LDS slot-swizzled (conflict-free reads).
// ---------------------------------------------------------------------------
__global__ __launch_bounds__(256)
void attn_stats_mfma(const __bf16* __restrict__ Qt, const __bf16* __restrict__ Kt,
                     float* __restrict__ rmp, float* __restrict__ rlp)
{
    __shared__ __bf16 Qs[128 * 32];
    __shared__ __bf16 Ks[128 * 32];
    __shared__ float redm[2][128];
    __shared__ float redl[2][128];

    const int t  = threadIdx.x;
    const int i0 = blockIdx.x * 128;
    const int mbo = blockIdx.y;
    const int o  = mbo >> 1, b = mbo & 1;
    const int seg = blockIdx.z;
    const int jbase = seg * 1024;
    const int mbK = o * 2 + b, mbQ = (1 - o) * 2 + b;

    const __bf16* Qg = Qt + (long)mbQ * 131072;
    const __bf16* Kg = Kt + (long)mbK * 131072;

    const int lane = t & 63, quad = lane >> 4, l15 = lane & 15, w = t >> 6;
    const int mS = (w >> 1) * 64;
    const int nS = (w & 1) * 64;

    const int drow = w * 16 + (lane >> 2);                  // staging dest row
    const int ssl  = ((lane & 3) ^ ((lane >> 3) & 3)) * 16; // swizzled src slot
    const int rsl  = (quad ^ ((l15 >> 1) & 3)) << 4;        // swizzled read slot

    load_lds16((const char*)Qg + (long)(i0 + drow) * 64 + ssl, (char*)Qs + w * 1024);
    load_lds16((const char*)Qg + (long)(i0 + 64 + drow) * 64 + ssl,
               (char*)Qs + 4096 + w * 1024);
    __syncthreads();

    bf16x8 qa[4];
#pragma unroll
    for (int fi = 0; fi < 4; ++fi)
        qa[fi] = *(const bf16x8*)((const char*)Qs + (mS + 16 * fi + l15) * 64 + rsl);

    const f32x4 zero4 = (f32x4)0.f;
    float m_t[16], l_t[16];
#pragma unroll
    for (int e = 0; e < 16; ++e) { m_t[e] = -3.0e38f; l_t[e] = 0.f; }

    for (int j0 = jbase; j0 < jbase + 1024; j0 += 128) {
        __syncthreads();
        load_lds16((const char*)Kg + (long)(j0 + drow) * 64 + ssl, (char*)Ks + w * 1024);
        load_lds16((const char*)Kg + (long)(j0 + 64 + drow) * 64 + ssl,
                   (char*)Ks + 4096 + w * 1024);
        __syncthreads();

        bf16x8 kb[4];
#pragma unroll
        for (int fj = 0; fj < 4; ++fj)
            kb[fj] = *(const bf16x8*)((const char*)Ks + (nS + 16 * fj + l15) * 64 + rsl);
#pragma unroll
        for (int fi = 0; fi < 4; ++fi) {
            f32x4 sf[4];
#pragma unroll
            for (int fj = 0; fj < 4; ++fj)
                sf[fj] = __builtin_amdgcn_mfma_f32_16x16x32_bf16(qa[fi], kb[fj], zero4, 0, 0, 0);
#pragma unroll
            for (int r = 0; r < 4; ++r) {
                int e = fi * 4 + r;
                float a = fmaxf(fmaxf(sf[0][r], sf[1][r]), fmaxf(sf[2][r], sf[3][r]));
                float nm = fmaxf(m_t[e], a);
                float s = exp2f(sf[0][r] - nm) + exp2f(sf[1][r] - nm)
                        + exp2f(sf[2][r] - nm) + exp2f(sf[3][r] - nm);
                l_t[e] = l_t[e] * exp2f(m_t[e] - nm) + s;
                m_t[e] = nm;
            }
        }
    }

#pragma unroll
    for (int d = 1; d < 16; d <<= 1)
#pragma unroll
        for (int e = 0; e < 16; ++e) {
            float om = __shfl_xor(m_t[e], d, 64);
            float ol = __shfl_xor(l_t[e], d, 64);
            float nm = fmaxf(m_t[e], om);
            l_t[e] = l_t[e] * exp2f(m_t[e] - nm) + ol * exp2f(om - nm);
            m_t[e] = nm;
        }
    if (l15 == 0) {
#pragma unroll
        for (int fi = 0; fi < 4; ++fi)
#pragma unroll
            for (int r = 0; r < 4; ++r) {
                redm[w & 1][mS + 16 * fi + quad * 4 + r] = m_t[fi * 4 + r];
                redl[w & 1][mS + 16 * fi + quad * 4 + r] = l_t[fi * 4 + r];
            }
    }
    __syncthreads();
    if (t < 128) {
        float m0 = redm[0][t], m1 = redm[1][t];
        float l0 = redl[0][t], l1 = redl[1][t];
        float m = fmaxf(m0, m1);
        float l = l0 * exp2f(m0 - m) + l1 * exp2f(m1 - m);
        rmp[seg * 16384 + mbo * 4096 + i0 + t] = m;
        rlp[seg * 16384 + mbo * 4096 + i0 + t] = l;
    }
}

// ---------------------------------------------------------------------------
// Merge 4-segment stats: m = max, rl = 1/sum(l_s * 2^(m_s-m)). grid 64x256.
// ---------------------------------------------------------------------------
__global__ __launch_bounds__(256)
void stats_merge(const float* __restrict__ rmp, const float* __restrict__ rlp,
                 float* __restrict__ rmb, float* __restrict__ rlb)
{
    int idx = blockIdx.x * 256 + threadIdx.x;
    float m = rmp[idx];
#pragma unroll
    for (int s = 1; s < 4; ++s) m = fmaxf(m, rmp[s * 16384 + idx]);
    float l = 0.f;
#pragma unroll
    for (int s = 0; s < 4; ++s)
        l += rlp[s * 16384 + idx] * exp2f(rmp[s * 16384 + idx] - m);
    rmb[idx] = m;
    rlb[idx] = 1.f / l;
}

// ---------------------------------------------------------------------------
// Fused MFMA PV v4 (round 12, unchanged): i64, c256, j-step 64, 48KB LDS,
// 2 blocks/CU, XCD grouping, conflict-free swizzles.
// ---------------------------------------------------------------------------
__global__ __launch_bounds__(256, 2)
void attn_pv_mfma(const __bf16* __restrict__ Qt, const __bf16* __restrict__ Kt,
                  const __bf16* __restrict__ Vb,
                  float* __restrict__ part0, float* __restrict__ part1,
                  const float* __restrict__ rmb, const float* __restrict__ rlb)
{
    __shared__ __bf16 Qs[64 * 32];        // 4KB  [64 i][32ch]
    __shared__ __bf16 Ks[64 * 32];        // 4KB  [64 j][32ch]
    __shared__ __bf16 Vs[2 * 256 * 32];   // 32KB [2ks][256c][32j]
    __shared__ __bf16 Ps[64 * 64];        // 8KB  [64 i][64 j] swizzled

    const int t  = threadIdx.x;
    const int bx = blockIdx.x;
    const int grp = bx & 7;               // XCD group = (mb<<1)|seg
    const int i0  = (bx >> 3) * 64;
    const int seg = grp & 1;
    const int mb  = grp >> 1;
    const int o  = mb >> 1, b = mb & 1;
    const int mbQ = (1 - o) * 2 + b;
    const int jbase = seg * 2048;

    const __bf16* Qg = Qt + (long)mbQ * 131072;
    const __bf16* Kg = Kt + (long)mb * 131072;
    const __bf16* Vg = Vb + (long)mb * 1048576;
    const float* rm = rmb + mb * 4096;
    const float* rl = rlb + mb * 4096;

    const int lane = t & 63, quad = lane >> 4, l15 = lane & 15, w = t >> 6;
    const int iS = w * 16;                // this wave's S row block
    const int cw = w * 64;                // this wave's PV c block

    const int drow = w * 16 + (lane >> 2);                  // staging dest row
    const int ssl  = ((lane & 3) ^ ((lane >> 3) & 3)) * 16; // swizzled src slot
    const int rsl  = (quad ^ ((l15 >> 1) & 3)) << 4;        // swizzled read slot

    // Q stage (64 rows, 4KB)
    load_lds16((const char*)Qg + (long)(i0 + drow) * 64 + ssl, (char*)Qs + w * 1024);

    float mlv[4], rlv[4];
#pragma unroll
    for (int r = 0; r < 4; ++r) mlv[r] = rm[i0 + iS + quad * 4 + r];
#pragma unroll
    for (int fj = 0; fj < 4; ++fj) rlv[fj] = rl[i0 + 16 * fj + l15];

    f32x4 acc[4][4];
#pragma unroll
    for (int i = 0; i < 4; ++i)
#pragma unroll
        for (int j = 0; j < 4; ++j) acc[i][j] = (f32x4)0.f;
    const f32x4 zero4 = (f32x4)0.f;

    __syncthreads();
    const bf16x8 qa = *(const bf16x8*)((const char*)Qs + (iS + l15) * 64 + rsl);

    for (int j0 = jbase; j0 < jbase + 2048; j0 += 64) {
        __syncthreads();                    // prev-step consumers done
        load_lds16((const char*)Kg + (long)(j0 + drow) * 64 + ssl,
                   (char*)Ks + w * 1024);
        __syncthreads();                    // K ready (only K in flight)

        // issue V loads now; latency hides under S + P (drained at next barrier)
#pragma unroll
        for (int ii = 0; ii < 8; ++ii) {
            int ks = ii >> 2;
            int c  = (ii & 3) * 64 + drow;
            load_lds16((const char*)Vg + (long)c * 8192 + (long)(j0 + ks * 32) * 2 + ssl,
                       (char*)Vs + ii * 4096 + w * 1024);
        }

        // S = Q K^T for rows [iS,iS+16), cols [0,64)
        f32x4 sA[4];
#pragma unroll
        for (int fj = 0; fj < 4; ++fj) {
            bf16x8 kb = *(const bf16x8*)((const char*)Ks + (16 * fj + l15) * 64 + rsl);
            sA[fj] = __builtin_amdgcn_mfma_f32_16x16x32_bf16(qa, kb, zero4, 0, 0, 0);
        }
        // P = exp2(S - m) -> swizzled Ps
#pragma unroll
        for (int fj = 0; fj < 4; ++fj)
#pragma unroll
            for (int r = 0; r < 4; ++r) {
                int il = iS + quad * 4 + r;
                int boff = (il * 128 + (16 * fj + l15) * 2) ^ ((il & 7) << 4);
                *(__bf16*)((char*)Ps + boff) = f2b(exp2f(sA[fj][r] - mlv[r]));
            }
        __syncthreads();                    // P visible, V staged

#pragma unroll
        for (int ks = 0; ks < 2; ++ks) {
            bf16x8 va[4], pb[4];
#pragma unroll
            for (int fi = 0; fi < 4; ++fi)
                va[fi] = *(const bf16x8*)((const char*)Vs + ks * 16384 +
                                          (cw + 16 * fi + l15) * 64 + rsl);
#pragma unroll
            for (int fj = 0; fj < 4; ++fj) {
                int ip = 16 * fj + l15;
                int boff = (ip * 128 + ks * 64 + quad * 16) ^ ((ip & 7) << 4);
                pb[fj] = *(const bf16x8*)((const char*)Ps + boff);
            }
#pragma unroll
            for (int fi = 0; fi < 4; ++fi)
#pragma unroll
                for (int fj = 0; fj < 4; ++fj)
                    acc[fi][fj] = __builtin_amdgcn_mfma_f32_16x16x32_bf16(
                        va[fi], pb[fj], acc[fi][fj], 0, 0, 0);
        }
    }

    // partial store, rl folded here (acc * 1/l)
    float* pg = (seg ? part1 : part0) + (long)mb * 1048576;
#pragma unroll
    for (int fi = 0; fi < 4; ++fi) {
#pragma unroll
        for (int r = 0; r < 4; ++r) {
            int c = cw + 16 * fi + quad * 4 + r;
            float* zr = pg + (long)c * 4096;
#pragma unroll
            for (int fj = 0; fj < 4; ++fj)
                zr[i0 + 16 * fj + l15] = acc[fi][fj][r] * rlv[fj];
        }
    }
}

// ---------------------------------------------------------------------------
// z = gamma*(part0+part1) + conv, transposed bf16 store to Zt[pix][256].
// grid (128, 8, 4).
// ---------------------------------------------------------------------------
__global__ __launch_bounds__(256)
void zred_t(const float* __restrict__ p0, const float* __restrict__ p1,
            const float* __restrict__ convb, __bf16* __restrict__ Zt,
            const float* __restrict__ g_r, const float* __restrict__ g_d)
{
    __shared__ float tile[32][33];
    const int t = threadIdx.x;
    const int pix0 = blockIdx.x * 32;
    const int c0 = blockIdx.y * 32;
    const int mb = blockIdx.z;
    const int o = mb >> 1;
    const float gamma = (o ? g_d : g_r)[0];
    const long base = (long)mb * 1048576;

    int i = t >> 3, j4 = (t & 7) * 4;
    long row = base + (long)(c0 + i) * 4096 + pix0 + j4;
    float4 a = *(const float4*)&p0[row];
    float4 b = *(const float4*)&p1[row];
    float4 cv = *(const float4*)&convb[row];
    tile[i][j4 + 0] = gamma * (a.x + b.x) + cv.x;
    tile[i][j4 + 1] = gamma * (a.y + b.y) + cv.y;
    tile[i][j4 + 2] = gamma * (a.z + b.z) + cv.z;
    tile[i][j4 + 3] = gamma * (a.w + b.w) + cv.w;
    __syncthreads();
    int j = t >> 3, i4 = (t & 7) * 4;
    bf16x4 oq;
    oq.x = f2b(tile[i4 + 0][j]); oq.y = f2b(tile[i4 + 1][j]);
    oq.z = f2b(tile[i4 + 2][j]); oq.w = f2b(tile[i4 + 3][j]);
    *(bf16x4*)&Zt[(long)mb * NPIX * 256 + (long)(pix0 + j) * 256 + c0 + i4] = oq;
}

// ---------------------------------------------------------------------------
// Host launcher (ws layout unchanged — see round 10 comment)
// ---------------------------------------------------------------------------
extern "C" void kernel_launch(void* const* d_in, const int* in_sizes, int n_in,
                              void* d_out, int out_size, void* d_ws, size_t ws_size,
                              hipStream_t stream)
{
    const float* in_rgb = (const float*)d_in[0];
    const float* in_dsm = (const float*)d_in[1];
    auto P = [&](int i) { return (const float*)d_in[i]; };

    float* ws    = (float*)d_ws;
    float* conv  = ws;
    float* part0 = ws + 4194304;
    float* rmb   = ws + 8388608;
    float* rlb   = ws + 8404992;
    float* rmp   = part0;            // [4][4][4096] scratch, dead before pv
    float* rlp   = part0 + 65536;
    float* scA   = ws + 8486912;
    float* shB   = ws + 8487424;
    __bf16* zrow = (__bf16*)(ws + 8487936);
    __bf16* Wt   = (__bf16*)(ws + 8488192);
    __bf16* Xp   = (__bf16*)(ws + 9667840);
    float*  part1 = ws + 9667840;            // aliases Xp (dead after conv)
    __bf16* Qt   = (__bf16*)(ws + 13862144);
    __bf16* Kt   = (__bf16*)(ws + 14124288);
    __bf16* Vbb  = (__bf16*)(ws + 14386432);
    __bf16* Ct   = (__bf16*)(ws + 16483584);
    __bf16* Zt   = (__bf16*)(ws + 18580736);
    __bf16* Wq   = (__bf16*)(ws + 20677888);
    __bf16* Wk   = (__bf16*)(ws + 20710656);
    __bf16* Wv   = (__bf16*)(ws + 20743424);
    __bf16* Wu   = (__bf16*)(ws + 20808960);

    // prep
    prep_w<<<2307, 256, 0, stream>>>(
        P(2), P(18), P(3), P(4), P(5), P(6), P(7),
        P(19), P(20), P(21), P(22), P(23),
        Wt, scA, shB, zrow);
    prep_gw<<<512, 256, 0, stream>>>(
        P(9), P(25), P(11), P(27), P(13), P(29), P(15), P(31),
        Wq, Wk, Wv, Wu);
    xpose<<<dim3(128, 16, 4), 256, 0, stream>>>(in_rgb, in_dsm, Xp);

    // conv3x3 + BN + PReLU (v4: halo, 8 waves, 512 threads, 256 blocks)
    conv_mfma<<<dim3(16, 4, 4), 512, 0, stream>>>(
        Wt, Xp, zrow, scA, shB, P(8), P(24), conv);
    t256<<<dim3(128, 8, 4), 256, 0, stream>>>(conv, Ct);

    // q/k/v projections (Q pre-scaled by log2e -> exp2 softmax domain)
    proj_mfma<<<dim3(32, 1, 4), 256, 0, stream>>>(
        Wq, 32768, Ct, P(10), P(26), Qt, nullptr, nullptr, nullptr, nullptr,
        0, 1.4426950408889634f);
    proj_mfma<<<dim3(32, 1, 4), 256, 0, stream>>>(
        Wk, 32768, Ct, P(12), P(28), Kt, nullptr, nullptr, nullptr, nullptr,
        0, 1.0f);
    proj_mfma<<<dim3(32, 2, 4), 256, 0, stream>>>(
        Wv, 65536, Ct, P(14), P(30), nullptr, Vbb, nullptr, nullptr, nullptr,
        1, 1.0f);

    // online softmax stats (j-split x4, 512 blocks) + merge
    attn_stats_mfma<<<dim3(32, 4, 4), 256, 0, stream>>>(Qt, Kt, rmp, rlp);
    stats_merge<<<64, 256, 0, stream>>>(rmp, rlp, rmb, rlb);

    // fused PV v4 (linear grid 512, XCD-grouped, 2 blocks/CU)
    attn_pv_mfma<<<512, 256, 0, stream>>>(
        Qt, Kt, Vbb, part0, part1, rmb, rlb);

    // z = gamma*(p0+p1)+conv, transpose + bf16 -> Zt
    zred_t<<<dim3(128, 8, 4), 256, 0, stream>>>(
        part0, part1, conv, Zt, P(17), P(33));

    // up projection + input residual -> fp32 out
    proj_mfma<<<dim3(32, 4, 4), 256, 0, stream>>>(
        Wu, 131072, Zt, P(16), P(32), nullptr, nullptr, (float*)d_out,
        in_rgb, in_dsm, 2, 1.0f);
}